// Round 2
// baseline (1749.917 us; speedup 1.0000x reference)
//
#include <hip/hip_runtime.h>
#include <hip/hip_bf16.h>
#include <cstdint>
#include <cstddef>

// ---------------- problem constants ----------------
#define BB 8
#define NN 8192
#define MM 1024
#define SS 32
#define PTOT (BB*MM*SS)          // 262144
// threshold must match f32(0.2*0.2 computed in double) — NOT 0.2f*0.2f
__device__ __constant__ float kR2 = 0.039999999105930328f;

// ---------------- stats layout (float offsets in ws) ----------------
#define ST_SUM0L 0
#define ST_SQ0L  64
#define ST_SUM0F 128
#define ST_SQ0F  192
#define ST_SUM1  256
#define ST_SQ1   320
#define ST_SUM2  384
#define ST_SQ2   512
#define P_AL     640
#define P_BL     704
#define P_AF     768
#define P_BF     832
#define P_A1     896
#define P_B1     960
#define P_A2     1024
#define P_B2     1152
#define STATS_ZERO_BYTES (640*4)

// ws byte offsets
#define OFF_FPS   0u
#define OFF_STATS 32768u
#define OFF_X0    40960u
#define OFF_Z1    12623872u      // x0 ends at 40960 + 262144*48 = 12623872

// ==================================================================
// 1) FPS v5: 1 block/batch, 512 threads (8 waves), coords staged in LDS
//    (96KB), only tmp[16] kept in registers (computed -> cannot be
//    rematerialized; the R0 lesson: the compiler refuses to keep 48
//    re-loadable coordinate floats live and re-reads them from global
//    every iteration -> 56 VGPR / 1177us symptom).
//    LDS layout pairs points (2j,2j+1) of column t:
//      sxy[j][t] = (x0,x1,y0,y1)  -> ds_read_b128, 16B lane stride (no
//                                    bank conflicts, xpair/ypair land in
//                                    aligned VGPR pairs for v_pk f32)
//      sz [j][t] = (z0,z1)        -> ds_read_b64, 8B lane stride
//    point index p = (k<<9)|t, pair j = k>>1. Selection/tie-break logic
//    identical to the proven version (np.argmax semantics via u64 keys).
// ==================================================================
__global__ __launch_bounds__(512) void fps_kernel(const float* __restrict__ center,
                                                  int* __restrict__ fps_idx) {
  const int b = blockIdx.x;
  const int t = threadIdx.x;               // 0..511
  const int lane = t & 63, wid = t >> 6;   // 8 waves
  const float* cb = center + (size_t)b * NN * 3;
  __shared__ __align__(16) float4 sxy[8][512];   // 64KB
  __shared__ __align__(8)  float2 sz[8][512];    // 32KB
  __shared__ unsigned long long s_wkey[2][8];
  float tmp[16];
  // ---- stage coords into LDS (once) ----
#pragma unroll
  for (int k = 0; k < 16; ++k) {
    const int p = (k << 9) | t;
    const float x = cb[p * 3 + 0], y = cb[p * 3 + 1], z = cb[p * 3 + 2];
    const int j = k >> 1;
    if (k & 1) { sxy[j][t].y = x; sxy[j][t].w = y; sz[j][t].y = z; }
    else       { sxy[j][t].x = x; sxy[j][t].z = y; sz[j][t].x = z; }
    tmp[k] = 1e10f;
  }
  __syncthreads();
  int far = 0;
  for (int i = 0; i < MM; ++i) {
    if (t == 0) fps_idx[(b << 10) + i] = far;
    // centroid from LDS (uniform-address broadcast read)
    const int fk = far >> 9, fc = far & 511, fj = fk >> 1, fp = fk & 1;
    const float4 q  = sxy[fj][fc];
    const float2 qz = sz[fj][fc];
    const float cx = fp ? q.y : q.x;
    const float cy = fp ? q.w : q.z;
    const float cz = fp ? qz.y : qz.x;
    // ---- distance update, 2 points per LDS pair ----
#pragma unroll
    for (int j = 0; j < 8; ++j) {
#pragma clang fp contract(off)
      const float4 qq = sxy[j][t];
      const float2 pz = sz[j][t];
      const float dx0 = qq.x - cx, dx1 = qq.y - cx;
      const float dy0 = qq.z - cy, dy1 = qq.w - cy;
      const float dz0 = pz.x - cz, dz1 = pz.y - cz;
      float d0 = dx0 * dx0; d0 = d0 + dy0 * dy0; d0 = d0 + dz0 * dz0;
      float d1 = dx1 * dx1; d1 = d1 + dy1 * dy1; d1 = d1 + dz1 * dz1;
      tmp[2 * j]     = fminf(tmp[2 * j], d0);
      tmp[2 * j + 1] = fminf(tmp[2 * j + 1], d1);
    }
    // ---- tree-max of the 16 temps ----
    const float a0 = fmaxf(tmp[0], tmp[1]),   a1 = fmaxf(tmp[2], tmp[3]);
    const float a2 = fmaxf(tmp[4], tmp[5]),   a3 = fmaxf(tmp[6], tmp[7]);
    const float a4 = fmaxf(tmp[8], tmp[9]),   a5 = fmaxf(tmp[10], tmp[11]);
    const float a6 = fmaxf(tmp[12], tmp[13]), a7 = fmaxf(tmp[14], tmp[15]);
    const float b0 = fmaxf(a0, a1), b1 = fmaxf(a2, a3);
    const float b2 = fmaxf(a4, a5), b3 = fmaxf(a6, a7);
    const float c0 = fmaxf(b0, b1), c1 = fmaxf(b2, b3);
    const float lmax = fmaxf(c0, c1);
    // lowest global index among ties (descending k: lowest k wins last)
    int lidx = 0x7fffffff;
#pragma unroll
    for (int k = 15; k >= 0; --k)
      if (tmp[k] == lmax) lidx = (k << 9) | t;
    // pack: non-negative float bits are order-preserving; ~idx breaks ties low
    unsigned long long key =
        ((unsigned long long)__float_as_uint(lmax) << 32) | (unsigned)(~lidx);
    for (int off = 1; off < 64; off <<= 1) {
      const unsigned long long ok = __shfl_xor(key, off);
      key = (ok > key) ? ok : key;
    }
    if (lane == 0) s_wkey[i & 1][wid] = key;
    __syncthreads();
    const unsigned long long* sk = s_wkey[i & 1];
    unsigned long long best = sk[0];
#pragma unroll
    for (int w = 1; w < 8; ++w) { const unsigned long long o = sk[w]; best = (o > best) ? o : best; }
    far = (int)(~(unsigned)best);
  }
}

// ==================================================================
// 2) Ball query (first 32 smallest in-radius indices) + gather + concat
//    one wave per (b,m); also writes new_center/new_normal outputs
// ==================================================================
__global__ __launch_bounds__(256) void ball_gather_kernel(
    const float* __restrict__ center, const float* __restrict__ normal,
    const float* __restrict__ feature, const int* __restrict__ fps_idx,
    float* __restrict__ x0, float* __restrict__ out) {
  const int lane = threadIdx.x & 63;
  const int wq = (int)((blockIdx.x * blockDim.x + threadIdx.x) >> 6); // 0..8191
  const int b = wq >> 10, m = wq & 1023;
  const float* cb = center  + (size_t)b * NN * 3;
  const float* nb = normal  + (size_t)b * NN * 3;
  const float* fb = feature + (size_t)b * 6 * NN;
  const int pstar = fps_idx[(b << 10) + m];
  const float qx = cb[pstar * 3 + 0], qy = cb[pstar * 3 + 1], qz = cb[pstar * 3 + 2];
  if (lane < 3) {
    out[b * 3072 + lane * 1024 + m]         = cb[pstar * 3 + lane];   // new_center^T
    out[24576 + b * 3072 + lane * 1024 + m] = nb[pstar * 3 + lane];   // new_normal^T
  }
  const size_t pos_base = (size_t)((b << 10) + m) * SS;
  int total = 0;
  int first_p = -1;
  const float r2 = kR2;
  for (int base = 0; base < NN && total < SS; base += 64) {
    const int p = base + lane;
    const float ppx = cb[p * 3], ppy = cb[p * 3 + 1], ppz = cb[p * 3 + 2];
    const float dx = ppx - qx, dy = ppy - qy, dz = ppz - qz;
    float d2;
    {
#pragma clang fp contract(off)
      d2 = dx * dx;
      d2 = d2 + dy * dy;
      d2 = d2 + dz * dz;
    }
    const bool hit = d2 < r2;
    const unsigned long long msk = __ballot(hit);
    if (first_p < 0 && msk) first_p = base + (int)__builtin_ctzll(msk);
    const int rank = (int)__popcll(msk & ((1ull << lane) - 1ull));
    const int slot = total + rank;
    if (hit && slot < SS) {
      float4 v0, v1, v2;
      v0.x = dx; v0.y = dy; v0.z = dz;             // group_center - new_center
      v0.w = nb[p * 3 + 0];
      v1.x = nb[p * 3 + 1];
      v1.y = nb[p * 3 + 2];
      v1.z = fb[p];
      v1.w = fb[NN + p];
      v2.x = fb[2 * NN + p];
      v2.y = fb[3 * NN + p];
      v2.z = fb[4 * NN + p];
      v2.w = fb[5 * NN + p];
      float4* dst = (float4*)(x0 + (pos_base + (size_t)slot) * 12);
      dst[0] = v0; dst[1] = v1; dst[2] = v2;
    }
    total += (int)__popcll(msk);
  }
  if (total < SS) {                                // pad with first hit (ref semantics)
    if (first_p < 0) first_p = 0;
    const int p = first_p;
    const float ppx = cb[p * 3], ppy = cb[p * 3 + 1], ppz = cb[p * 3 + 2];
    float4 v0, v1, v2;
    v0.x = ppx - qx; v0.y = ppy - qy; v0.z = ppz - qz;
    v0.w = nb[p * 3 + 0]; v1.x = nb[p * 3 + 1]; v1.y = nb[p * 3 + 2];
    v1.z = fb[p]; v1.w = fb[NN + p];
    v2.x = fb[2 * NN + p]; v2.y = fb[3 * NN + p]; v2.z = fb[4 * NN + p]; v2.w = fb[5 * NN + p];
    for (int slot = total + lane; slot < SS; slot += 64) {
      float4* dst = (float4*)(x0 + (pos_base + (size_t)slot) * 12);
      dst[0] = v0; dst[1] = v1; dst[2] = v2;
    }
  }
}

// ==================================================================
// 3) stats for layer0 conv outputs (loc 64ch + ftr 64ch), lane = channel
// ==================================================================
__global__ __launch_bounds__(256) void stats0_kernel(
    const float* __restrict__ x0,
    const float* __restrict__ w_l0, const float* __restrict__ b_l0,
    const float* __restrict__ w_f0, const float* __restrict__ b_f0,
    float* __restrict__ stats) {
  const int lane = threadIdx.x & 63, wid = threadIdx.x >> 6;
  const int wgid = blockIdx.x * 4 + wid;           // 0..2047
  float wl[3], wf[9];
#pragma unroll
  for (int j = 0; j < 3; ++j) wl[j] = w_l0[lane * 3 + j];
#pragma unroll
  for (int j = 0; j < 9; ++j) wf[j] = w_f0[lane * 9 + j];
  const float bl = b_l0[lane], bf = b_f0[lane];
  float sL = 0.f, qL = 0.f, sF = 0.f, qF = 0.f;
  for (int it = 0; it < 128; ++it) {
    const int p = it * 2048 + wgid;
    const float4* row = (const float4*)(x0 + (size_t)p * 12);
    const float4 r0 = row[0], r1 = row[1], r2 = row[2];
    const float yL = bl + wl[0] * r0.x + wl[1] * r0.y + wl[2] * r0.z;
    const float yF = bf + wf[0] * r0.w + wf[1] * r1.x + wf[2] * r1.y + wf[3] * r1.z +
                     wf[4] * r1.w + wf[5] * r2.x + wf[6] * r2.y + wf[7] * r2.z + wf[8] * r2.w;
    sL += yL; qL += yL * yL; sF += yF; qF += yF * yF;
  }
  __shared__ float red[4][64][4];
  red[wid][lane][0] = sL; red[wid][lane][1] = qL;
  red[wid][lane][2] = sF; red[wid][lane][3] = qF;
  __syncthreads();
  if (wid == 0) {
    float a0 = 0.f, a1 = 0.f, a2 = 0.f, a3 = 0.f;
    for (int w = 0; w < 4; ++w) {
      a0 += red[w][lane][0]; a1 += red[w][lane][1];
      a2 += red[w][lane][2]; a3 += red[w][lane][3];
    }
    atomicAdd(&stats[ST_SUM0L + lane], a0);
    atomicAdd(&stats[ST_SQ0L + lane], a1);
    atomicAdd(&stats[ST_SUM0F + lane], a2);
    atomicAdd(&stats[ST_SQ0F + lane], a3);
  }
}

// ==================================================================
// finalize kernels: sums -> (a, b') with y_norm = a*y + b'
// ==================================================================
__global__ void finalize0_kernel(float* stats, const float* gl, const float* bel,
                                 const float* gf, const float* bef) {
  const int t = threadIdx.x;                        // 128
  const float invN = 1.0f / (float)PTOT;
  if (t < 64) {
    const float mean = stats[ST_SUM0L + t] * invN;
    const float var  = stats[ST_SQ0L + t] * invN - mean * mean;
    const float a = gl[t] / sqrtf(var + 1e-5f);
    stats[P_AL + t] = a;
    stats[P_BL + t] = bel[t] - a * mean;
  } else {
    const int c = t - 64;
    const float mean = stats[ST_SUM0F + c] * invN;
    const float var  = stats[ST_SQ0F + c] * invN - mean * mean;
    const float a = gf[c] / sqrtf(var + 1e-5f);
    stats[P_AF + c] = a;
    stats[P_BF + c] = bef[c] - a * mean;
  }
}
__global__ void finalize1_kernel(float* stats, const float* g, const float* be) {
  const int t = threadIdx.x;                        // 64
  const float invN = 1.0f / (float)PTOT;
  const float mean = stats[ST_SUM1 + t] * invN;
  const float var  = stats[ST_SQ1 + t] * invN - mean * mean;
  const float a = g[t] / sqrtf(var + 1e-5f);
  stats[P_A1 + t] = a;
  stats[P_B1 + t] = be[t] - a * mean;
}
__global__ void finalize2_kernel(float* stats, const float* g, const float* be) {
  const int t = threadIdx.x;                        // 128
  const float invN = 1.0f / (float)PTOT;
  const float mean = stats[ST_SUM2 + t] * invN;
  const float var  = stats[ST_SQ2 + t] * invN - mean * mean;
  const float a = g[t] / sqrtf(var + 1e-5f);
  stats[P_A2 + t] = a;
  stats[P_B2 + t] = be[t] - a * mean;
}

// ==================================================================
// 5) conv0 + BN0 + relu  ->  conv1 (z1 stored f32) + stats1
//    lane = output channel; per-position x1 broadcast via wave-private LDS
// ==================================================================
__global__ __launch_bounds__(256) void k5_kernel(
    const float* __restrict__ x0, float* __restrict__ z1,
    float* __restrict__ stats,
    const float* __restrict__ w_l0, const float* __restrict__ b_l0,
    const float* __restrict__ w_f0, const float* __restrict__ b_f0,
    const float* __restrict__ w1, const float* __restrict__ b1) {
  const int lane = threadIdx.x & 63, wid = threadIdx.x >> 6;
  const int wgid = blockIdx.x * 4 + wid;
  float wl[3], wf[9], w1r[64];
#pragma unroll
  for (int j = 0; j < 3; ++j) wl[j] = w_l0[lane * 3 + j];
#pragma unroll
  for (int j = 0; j < 9; ++j) wf[j] = w_f0[lane * 9 + j];
#pragma unroll
  for (int k = 0; k < 64; ++k) w1r[k] = w1[lane * 64 + k];
  const float bl = b_l0[lane], bf = b_f0[lane], b1v = b1[lane];
  const float aL = stats[P_AL + lane], bL = stats[P_BL + lane];
  const float aF = stats[P_AF + lane], bF = stats[P_BF + lane];
  float s1 = 0.f, q1 = 0.f;
  __shared__ __align__(16) float sx[2][4][64];
  for (int it = 0; it < 128; ++it) {
    const int p = it * 2048 + wgid;
    const float4* row = (const float4*)(x0 + (size_t)p * 12);
    const float4 r0 = row[0], r1 = row[1], r2 = row[2];
    const float yL = bl + wl[0] * r0.x + wl[1] * r0.y + wl[2] * r0.z;
    const float yF = bf + wf[0] * r0.w + wf[1] * r1.x + wf[2] * r1.y + wf[3] * r1.z +
                     wf[4] * r1.w + wf[5] * r2.x + wf[6] * r2.y + wf[7] * r2.z + wf[8] * r2.w;
    const float x1 = fmaxf(aL * yL + bL + (aF * yF + bF), 0.f);
    sx[it & 1][wid][lane] = x1;
    __syncthreads();
    float acc = b1v;
    const float4* xv = (const float4*)&sx[it & 1][wid][0];
#pragma unroll
    for (int k4 = 0; k4 < 16; ++k4) {
      const float4 xq = xv[k4];
      acc += w1r[4 * k4 + 0] * xq.x + w1r[4 * k4 + 1] * xq.y +
             w1r[4 * k4 + 2] * xq.z + w1r[4 * k4 + 3] * xq.w;
    }
    s1 += acc; q1 += acc * acc;
    z1[(size_t)p * 64 + lane] = acc;
  }
  __shared__ float red[4][64][2];
  red[wid][lane][0] = s1; red[wid][lane][1] = q1;
  __syncthreads();
  if (wid == 0) {
    float a0 = 0.f, a1v = 0.f;
    for (int w = 0; w < 4; ++w) { a0 += red[w][lane][0]; a1v += red[w][lane][1]; }
    atomicAdd(&stats[ST_SUM1 + lane], a0);
    atomicAdd(&stats[ST_SQ1 + lane], a1v);
  }
}

// ==================================================================
// 6) BN1+relu -> conv2 (128ch) + stats2; z2 written bf16 IN-PLACE over z1
// ==================================================================
__global__ __launch_bounds__(256, 2) void k6_kernel(
    float* __restrict__ z12, float* __restrict__ stats,
    const float* __restrict__ w2, const float* __restrict__ b2) {
  const int lane = threadIdx.x & 63, wid = threadIdx.x >> 6;
  const int wgid = blockIdx.x * 4 + wid;
  float w2a[64], w2b[64];
#pragma unroll
  for (int k = 0; k < 64; ++k) w2a[k] = w2[lane * 64 + k];
#pragma unroll
  for (int k = 0; k < 64; ++k) w2b[k] = w2[(lane + 64) * 64 + k];
  const float b2a = b2[lane], b2b = b2[lane + 64];
  const float a1 = stats[P_A1 + lane], b1p = stats[P_B1 + lane];
  float s0 = 0.f, q0 = 0.f, s1 = 0.f, q1 = 0.f;
  __shared__ __align__(16) float sx[2][4][64];
  __hip_bfloat16* zo = (__hip_bfloat16*)z12;
  for (int it = 0; it < 128; ++it) {
    const int p = it * 2048 + wgid;
    const float z = z12[(size_t)p * 64 + lane];
    const float x2 = fmaxf(a1 * z + b1p, 0.f);
    sx[it & 1][wid][lane] = x2;
    __syncthreads();
    float acc0 = b2a, acc1 = b2b;
    const float4* xv = (const float4*)&sx[it & 1][wid][0];
#pragma unroll
    for (int k4 = 0; k4 < 16; ++k4) {
      const float4 xq = xv[k4];
      acc0 += w2a[4 * k4] * xq.x + w2a[4 * k4 + 1] * xq.y + w2a[4 * k4 + 2] * xq.z + w2a[4 * k4 + 3] * xq.w;
      acc1 += w2b[4 * k4] * xq.x + w2b[4 * k4 + 1] * xq.y + w2b[4 * k4 + 2] * xq.z + w2b[4 * k4 + 3] * xq.w;
    }
    s0 += acc0; q0 += acc0 * acc0; s1 += acc1; q1 += acc1 * acc1;
    zo[(size_t)p * 128 + lane]      = __float2bfloat16(acc0);
    zo[(size_t)p * 128 + 64 + lane] = __float2bfloat16(acc1);
  }
  __shared__ float red[4][64][4];
  red[wid][lane][0] = s0; red[wid][lane][1] = q0;
  red[wid][lane][2] = s1; red[wid][lane][3] = q1;
  __syncthreads();
  if (wid == 0) {
    float t0 = 0.f, t1 = 0.f, t2 = 0.f, t3 = 0.f;
    for (int w = 0; w < 4; ++w) {
      t0 += red[w][lane][0]; t1 += red[w][lane][1];
      t2 += red[w][lane][2]; t3 += red[w][lane][3];
    }
    atomicAdd(&stats[ST_SUM2 + lane], t0);
    atomicAdd(&stats[ST_SQ2 + lane], t1);
    atomicAdd(&stats[ST_SUM2 + 64 + lane], t2);
    atomicAdd(&stats[ST_SQ2 + 64 + lane], t3);
  }
}

// ==================================================================
// 7) BN2 + relu + max over nsample, transposed write via LDS tile
//    block = (b, 64-m tile); out x shape (8,128,1024)
// ==================================================================
__global__ __launch_bounds__(256) void k7_kernel(const __hip_bfloat16* __restrict__ z2,
                                                 const float* __restrict__ stats,
                                                 float* __restrict__ out3) {
  const int b = blockIdx.x >> 4;
  const int mt = blockIdx.x & 15;
  const int t = threadIdx.x;
  const int o = t & 127, h = t >> 7;
  const float a = stats[P_A2 + o], bb = stats[P_B2 + o];
  __shared__ float tile[128][65];
  for (int j = 0; j < 32; ++j) {
    const int ml = h + 2 * j;
    const size_t rowbase = ((size_t)(b * 1024 + mt * 64 + ml)) * SS;
    float acc = -1e30f;
    for (int s = 0; s < SS; ++s) {
      const float v = __bfloat162float(z2[(rowbase + s) * 128 + o]);
      acc = fmaxf(acc, a * v + bb);
    }
    tile[o][ml] = fmaxf(acc, 0.f);                 // relu after max (monotone)
  }
  __syncthreads();
  const int r = t >> 1, c0 = (t & 1) * 32;
  float* dst = out3 + (size_t)b * 128 * 1024 + (size_t)r * 1024 + mt * 64 + c0;
  for (int j = 0; j < 32; ++j) dst[j] = tile[r][c0 + j];
}

// ==================================================================
extern "C" void kernel_launch(void* const* d_in, const int* in_sizes, int n_in,
                              void* d_out, int out_size, void* d_ws, size_t ws_size,
                              hipStream_t stream) {
  const float* center  = (const float*)d_in[0];
  const float* normal  = (const float*)d_in[1];
  const float* feature = (const float*)d_in[2];
  const float* w_l0 = (const float*)d_in[3];
  const float* b_l0 = (const float*)d_in[4];
  const float* g_l0 = (const float*)d_in[5];
  const float* be_l0 = (const float*)d_in[6];
  const float* w_f0 = (const float*)d_in[7];
  const float* b_f0 = (const float*)d_in[8];
  const float* g_f0 = (const float*)d_in[9];
  const float* be_f0 = (const float*)d_in[10];
  const float* w1 = (const float*)d_in[11];
  const float* b1 = (const float*)d_in[12];
  const float* g1 = (const float*)d_in[13];
  const float* be1 = (const float*)d_in[14];
  const float* w2 = (const float*)d_in[15];
  const float* b2 = (const float*)d_in[16];
  const float* g2 = (const float*)d_in[17];
  const float* be2 = (const float*)d_in[18];
  float* out = (float*)d_out;
  char* ws = (char*)d_ws;
  int*   fps_idx = (int*)(ws + OFF_FPS);
  float* stats   = (float*)(ws + OFF_STATS);
  float* x0      = (float*)(ws + OFF_X0);
  float* z1      = (float*)(ws + OFF_Z1);

  hipMemsetAsync(stats, 0, STATS_ZERO_BYTES, stream);
  hipLaunchKernelGGL(fps_kernel, dim3(8), dim3(512), 0, stream, center, fps_idx);
  hipLaunchKernelGGL(ball_gather_kernel, dim3(2048), dim3(256), 0, stream,
                     center, normal, feature, fps_idx, x0, out);
  hipLaunchKernelGGL(stats0_kernel, dim3(512), dim3(256), 0, stream,
                     x0, w_l0, b_l0, w_f0, b_f0, stats);
  hipLaunchKernelGGL(finalize0_kernel, dim3(1), dim3(128), 0, stream,
                     stats, g_l0, be_l0, g_f0, be_f0);
  hipLaunchKernelGGL(k5_kernel, dim3(512), dim3(256), 0, stream,
                     x0, z1, stats, w_l0, b_l0, w_f0, b_f0, w1, b1);
  hipLaunchKernelGGL(finalize1_kernel, dim3(1), dim3(64), 0, stream, stats, g1, be1);
  hipLaunchKernelGGL(k6_kernel, dim3(512), dim3(256), 0, stream, z1, stats, w2, b2);
  hipLaunchKernelGGL(finalize2_kernel, dim3(1), dim3(128), 0, stream, stats, g2, be2);
  hipLaunchKernelGGL(k7_kernel, dim3(128), dim3(256), 0, stream,
                     (const __hip_bfloat16*)z1, stats, out + 49152);
}

// Round 3
// 1503.326 us; speedup vs baseline: 1.1640x; 1.1640x over previous
//
#include <hip/hip_runtime.h>
#include <hip/hip_bf16.h>
#include <cstdint>
#include <cstddef>

// ---------------- problem constants ----------------
#define BB 8
#define NN 8192
#define MM 1024
#define SS 32
#define PTOT (BB*MM*SS)          // 262144
// threshold must match f32(0.2*0.2 computed in double) — NOT 0.2f*0.2f
__device__ __constant__ float kR2 = 0.039999999105930328f;

// ---------------- stats layout (float offsets in ws) ----------------
#define ST_SUM0L 0
#define ST_SQ0L  64
#define ST_SUM0F 128
#define ST_SQ0F  192
#define ST_SUM1  256
#define ST_SQ1   320
#define ST_SUM2  384
#define ST_SQ2   512
#define P_AL     640
#define P_BL     704
#define P_AF     768
#define P_BF     832
#define P_A1     896
#define P_B1     960
#define P_A2     1024
#define P_B2     1152
#define STATS_ZERO_BYTES (640*4)

// ws byte offsets
#define OFF_FPS   0u
#define OFF_STATS 32768u
#define OFF_X0    40960u
#define OFF_Z1    12623872u      // x0 ends at 40960 + 262144*48 = 12623872

typedef float v2f __attribute__((ext_vector_type(2)));

// ==================================================================
// 1) FPS v6: coords pinned in REGISTERS via asm "+v" (an asm result
//    cannot be rematerialized -> allocator must keep them live; R0/R2
//    lesson: both L1 re-load (56 VGPR, 1177us) and LDS re-read (192B/
//    thread/iter, 1326us) are bandwidth-bound at ~the same cost as the
//    math). State: 8x {X,Y,Z,T} float2 pairs = 64 VGPR. Distance math on
//    <2 x float> -> v_pk_add/mul_f32 (packed f32, gfx90a+), identical
//    per-element op order (contract off) -> bit-identical results.
//    Centroid broadcast via 128KB LDS float4 table (1 uniform
//    ds_read_b128/iter, the only LDS traffic in the loop).
//    Selection/tie-break/u64-key butterfly: the proven logic, unchanged.
// ==================================================================
__global__ __launch_bounds__(512, 2) void fps_kernel(const float* __restrict__ center,
                                                     int* __restrict__ fps_idx) {
  const int b = blockIdx.x;
  const int t = threadIdx.x;               // 0..511
  const int lane = t & 63, wid = t >> 6;   // 8 waves
  const float* cb = center + (size_t)b * NN * 3;
  __shared__ __align__(16) float4 sc[NN];            // 128 KB centroid table
  __shared__ unsigned long long s_wkey[2][8];
  v2f X[8], Y[8], Z[8], T[8];
#pragma unroll
  for (int j = 0; j < 8; ++j) {
    const int p0 = ((2 * j) << 9) | t;
    const int p1 = ((2 * j + 1) << 9) | t;
    const float x0 = cb[p0 * 3 + 0], y0 = cb[p0 * 3 + 1], z0 = cb[p0 * 3 + 2];
    const float x1 = cb[p1 * 3 + 0], y1 = cb[p1 * 3 + 1], z1 = cb[p1 * 3 + 2];
    sc[p0] = make_float4(x0, y0, z0, 0.f);
    sc[p1] = make_float4(x1, y1, z1, 0.f);
    X[j] = (v2f){x0, x1}; Y[j] = (v2f){y0, y1}; Z[j] = (v2f){z0, z1};
    T[j] = (v2f){1e10f, 1e10f};
    // pin: make the coord values asm-defined so they CANNOT be
    // rematerialized from memory; forces residency in VGPRs.
    asm volatile("" : "+v"(X[j]), "+v"(Y[j]), "+v"(Z[j]));
  }
  __syncthreads();
  int far = 0;
  for (int i = 0; i < MM; ++i) {
    if (t == 0) fps_idx[(b << 10) + i] = far;
    // centroid: uniform-address LDS broadcast read
    const float4 c = sc[__builtin_amdgcn_readfirstlane(far)];
    const v2f cx2 = (v2f){c.x, c.x};
    const v2f cy2 = (v2f){c.y, c.y};
    const v2f cz2 = (v2f){c.z, c.z};
    {
#pragma clang fp contract(off)
#pragma unroll
      for (int j = 0; j < 8; ++j) {
        const v2f dx = X[j] - cx2;
        const v2f dy = Y[j] - cy2;
        const v2f dz = Z[j] - cz2;
        v2f d = dx * dx;
        d = d + dy * dy;
        d = d + dz * dz;
        T[j].x = fminf(T[j].x, d.x);
        T[j].y = fminf(T[j].y, d.y);
      }
    }
    // ---- tree-max of the 16 temps ----
    const float a0 = fmaxf(T[0].x, T[0].y), a1 = fmaxf(T[1].x, T[1].y);
    const float a2 = fmaxf(T[2].x, T[2].y), a3 = fmaxf(T[3].x, T[3].y);
    const float a4 = fmaxf(T[4].x, T[4].y), a5 = fmaxf(T[5].x, T[5].y);
    const float a6 = fmaxf(T[6].x, T[6].y), a7 = fmaxf(T[7].x, T[7].y);
    const float b0 = fmaxf(a0, a1), b1 = fmaxf(a2, a3);
    const float b2 = fmaxf(a4, a5), b3 = fmaxf(a6, a7);
    const float c0 = fmaxf(b0, b1), c1 = fmaxf(b2, b3);
    const float lmax = fmaxf(c0, c1);
    // lowest global index among ties (descending k: lowest k assigned last)
    int lidx = 0x7fffffff;
#pragma unroll
    for (int j = 7; j >= 0; --j) {
      if (T[j].y == lmax) lidx = ((2 * j + 1) << 9) | t;
      if (T[j].x == lmax) lidx = ((2 * j) << 9) | t;
    }
    // pack: non-negative float bits are order-preserving; ~idx breaks ties low
    unsigned long long key =
        ((unsigned long long)__float_as_uint(lmax) << 32) | (unsigned)(~lidx);
    for (int off = 1; off < 64; off <<= 1) {
      const unsigned long long ok = __shfl_xor(key, off);
      key = (ok > key) ? ok : key;
    }
    if (lane == 0) s_wkey[i & 1][wid] = key;
    __syncthreads();
    const unsigned long long* sk = s_wkey[i & 1];
    unsigned long long best = sk[0];
#pragma unroll
    for (int w = 1; w < 8; ++w) { const unsigned long long o = sk[w]; best = (o > best) ? o : best; }
    far = (int)(~(unsigned)best);
  }
}

// ==================================================================
// 2) Ball query (first 32 smallest in-radius indices) + gather + concat
//    one wave per (b,m); also writes new_center/new_normal outputs
// ==================================================================
__global__ __launch_bounds__(256) void ball_gather_kernel(
    const float* __restrict__ center, const float* __restrict__ normal,
    const float* __restrict__ feature, const int* __restrict__ fps_idx,
    float* __restrict__ x0, float* __restrict__ out) {
  const int lane = threadIdx.x & 63;
  const int wq = (int)((blockIdx.x * blockDim.x + threadIdx.x) >> 6); // 0..8191
  const int b = wq >> 10, m = wq & 1023;
  const float* cb = center  + (size_t)b * NN * 3;
  const float* nb = normal  + (size_t)b * NN * 3;
  const float* fb = feature + (size_t)b * 6 * NN;
  const int pstar = fps_idx[(b << 10) + m];
  const float qx = cb[pstar * 3 + 0], qy = cb[pstar * 3 + 1], qz = cb[pstar * 3 + 2];
  if (lane < 3) {
    out[b * 3072 + lane * 1024 + m]         = cb[pstar * 3 + lane];   // new_center^T
    out[24576 + b * 3072 + lane * 1024 + m] = nb[pstar * 3 + lane];   // new_normal^T
  }
  const size_t pos_base = (size_t)((b << 10) + m) * SS;
  int total = 0;
  int first_p = -1;
  const float r2 = kR2;
  for (int base = 0; base < NN && total < SS; base += 64) {
    const int p = base + lane;
    const float ppx = cb[p * 3], ppy = cb[p * 3 + 1], ppz = cb[p * 3 + 2];
    const float dx = ppx - qx, dy = ppy - qy, dz = ppz - qz;
    float d2;
    {
#pragma clang fp contract(off)
      d2 = dx * dx;
      d2 = d2 + dy * dy;
      d2 = d2 + dz * dz;
    }
    const bool hit = d2 < r2;
    const unsigned long long msk = __ballot(hit);
    if (first_p < 0 && msk) first_p = base + (int)__builtin_ctzll(msk);
    const int rank = (int)__popcll(msk & ((1ull << lane) - 1ull));
    const int slot = total + rank;
    if (hit && slot < SS) {
      float4 v0, v1, v2;
      v0.x = dx; v0.y = dy; v0.z = dz;             // group_center - new_center
      v0.w = nb[p * 3 + 0];
      v1.x = nb[p * 3 + 1];
      v1.y = nb[p * 3 + 2];
      v1.z = fb[p];
      v1.w = fb[NN + p];
      v2.x = fb[2 * NN + p];
      v2.y = fb[3 * NN + p];
      v2.z = fb[4 * NN + p];
      v2.w = fb[5 * NN + p];
      float4* dst = (float4*)(x0 + (pos_base + (size_t)slot) * 12);
      dst[0] = v0; dst[1] = v1; dst[2] = v2;
    }
    total += (int)__popcll(msk);
  }
  if (total < SS) {                                // pad with first hit (ref semantics)
    if (first_p < 0) first_p = 0;
    const int p = first_p;
    const float ppx = cb[p * 3], ppy = cb[p * 3 + 1], ppz = cb[p * 3 + 2];
    float4 v0, v1, v2;
    v0.x = ppx - qx; v0.y = ppy - qy; v0.z = ppz - qz;
    v0.w = nb[p * 3 + 0]; v1.x = nb[p * 3 + 1]; v1.y = nb[p * 3 + 2];
    v1.z = fb[p]; v1.w = fb[NN + p];
    v2.x = fb[2 * NN + p]; v2.y = fb[3 * NN + p]; v2.z = fb[4 * NN + p]; v2.w = fb[5 * NN + p];
    for (int slot = total + lane; slot < SS; slot += 64) {
      float4* dst = (float4*)(x0 + (pos_base + (size_t)slot) * 12);
      dst[0] = v0; dst[1] = v1; dst[2] = v2;
    }
  }
}

// ==================================================================
// 3) stats for layer0 conv outputs (loc 64ch + ftr 64ch), lane = channel
// ==================================================================
__global__ __launch_bounds__(256) void stats0_kernel(
    const float* __restrict__ x0,
    const float* __restrict__ w_l0, const float* __restrict__ b_l0,
    const float* __restrict__ w_f0, const float* __restrict__ b_f0,
    float* __restrict__ stats) {
  const int lane = threadIdx.x & 63, wid = threadIdx.x >> 6;
  const int wgid = blockIdx.x * 4 + wid;           // 0..2047
  float wl[3], wf[9];
#pragma unroll
  for (int j = 0; j < 3; ++j) wl[j] = w_l0[lane * 3 + j];
#pragma unroll
  for (int j = 0; j < 9; ++j) wf[j] = w_f0[lane * 9 + j];
  const float bl = b_l0[lane], bf = b_f0[lane];
  float sL = 0.f, qL = 0.f, sF = 0.f, qF = 0.f;
  for (int it = 0; it < 128; ++it) {
    const int p = it * 2048 + wgid;
    const float4* row = (const float4*)(x0 + (size_t)p * 12);
    const float4 r0 = row[0], r1 = row[1], r2 = row[2];
    const float yL = bl + wl[0] * r0.x + wl[1] * r0.y + wl[2] * r0.z;
    const float yF = bf + wf[0] * r0.w + wf[1] * r1.x + wf[2] * r1.y + wf[3] * r1.z +
                     wf[4] * r1.w + wf[5] * r2.x + wf[6] * r2.y + wf[7] * r2.z + wf[8] * r2.w;
    sL += yL; qL += yL * yL; sF += yF; qF += yF * yF;
  }
  __shared__ float red[4][64][4];
  red[wid][lane][0] = sL; red[wid][lane][1] = qL;
  red[wid][lane][2] = sF; red[wid][lane][3] = qF;
  __syncthreads();
  if (wid == 0) {
    float a0 = 0.f, a1 = 0.f, a2 = 0.f, a3 = 0.f;
    for (int w = 0; w < 4; ++w) {
      a0 += red[w][lane][0]; a1 += red[w][lane][1];
      a2 += red[w][lane][2]; a3 += red[w][lane][3];
    }
    atomicAdd(&stats[ST_SUM0L + lane], a0);
    atomicAdd(&stats[ST_SQ0L + lane], a1);
    atomicAdd(&stats[ST_SUM0F + lane], a2);
    atomicAdd(&stats[ST_SQ0F + lane], a3);
  }
}

// ==================================================================
// finalize kernels: sums -> (a, b') with y_norm = a*y + b'
// ==================================================================
__global__ void finalize0_kernel(float* stats, const float* gl, const float* bel,
                                 const float* gf, const float* bef) {
  const int t = threadIdx.x;                        // 128
  const float invN = 1.0f / (float)PTOT;
  if (t < 64) {
    const float mean = stats[ST_SUM0L + t] * invN;
    const float var  = stats[ST_SQ0L + t] * invN - mean * mean;
    const float a = gl[t] / sqrtf(var + 1e-5f);
    stats[P_AL + t] = a;
    stats[P_BL + t] = bel[t] - a * mean;
  } else {
    const int c = t - 64;
    const float mean = stats[ST_SUM0F + c] * invN;
    const float var  = stats[ST_SQ0F + c] * invN - mean * mean;
    const float a = gf[c] / sqrtf(var + 1e-5f);
    stats[P_AF + c] = a;
    stats[P_BF + c] = bef[c] - a * mean;
  }
}
__global__ void finalize1_kernel(float* stats, const float* g, const float* be) {
  const int t = threadIdx.x;                        // 64
  const float invN = 1.0f / (float)PTOT;
  const float mean = stats[ST_SUM1 + t] * invN;
  const float var  = stats[ST_SQ1 + t] * invN - mean * mean;
  const float a = g[t] / sqrtf(var + 1e-5f);
  stats[P_A1 + t] = a;
  stats[P_B1 + t] = be[t] - a * mean;
}
__global__ void finalize2_kernel(float* stats, const float* g, const float* be) {
  const int t = threadIdx.x;                        // 128
  const float invN = 1.0f / (float)PTOT;
  const float mean = stats[ST_SUM2 + t] * invN;
  const float var  = stats[ST_SQ2 + t] * invN - mean * mean;
  const float a = g[t] / sqrtf(var + 1e-5f);
  stats[P_A2 + t] = a;
  stats[P_B2 + t] = be[t] - a * mean;
}

// ==================================================================
// 5) conv0 + BN0 + relu  ->  conv1 (z1 stored f32) + stats1
//    lane = output channel; per-position x1 broadcast via wave-private LDS
// ==================================================================
__global__ __launch_bounds__(256) void k5_kernel(
    const float* __restrict__ x0, float* __restrict__ z1,
    float* __restrict__ stats,
    const float* __restrict__ w_l0, const float* __restrict__ b_l0,
    const float* __restrict__ w_f0, const float* __restrict__ b_f0,
    const float* __restrict__ w1, const float* __restrict__ b1) {
  const int lane = threadIdx.x & 63, wid = threadIdx.x >> 6;
  const int wgid = blockIdx.x * 4 + wid;
  float wl[3], wf[9], w1r[64];
#pragma unroll
  for (int j = 0; j < 3; ++j) wl[j] = w_l0[lane * 3 + j];
#pragma unroll
  for (int j = 0; j < 9; ++j) wf[j] = w_f0[lane * 9 + j];
#pragma unroll
  for (int k = 0; k < 64; ++k) w1r[k] = w1[lane * 64 + k];
  const float bl = b_l0[lane], bf = b_f0[lane], b1v = b1[lane];
  const float aL = stats[P_AL + lane], bL = stats[P_BL + lane];
  const float aF = stats[P_AF + lane], bF = stats[P_BF + lane];
  float s1 = 0.f, q1 = 0.f;
  __shared__ __align__(16) float sx[2][4][64];
  for (int it = 0; it < 128; ++it) {
    const int p = it * 2048 + wgid;
    const float4* row = (const float4*)(x0 + (size_t)p * 12);
    const float4 r0 = row[0], r1 = row[1], r2 = row[2];
    const float yL = bl + wl[0] * r0.x + wl[1] * r0.y + wl[2] * r0.z;
    const float yF = bf + wf[0] * r0.w + wf[1] * r1.x + wf[2] * r1.y + wf[3] * r1.z +
                     wf[4] * r1.w + wf[5] * r2.x + wf[6] * r2.y + wf[7] * r2.z + wf[8] * r2.w;
    const float x1 = fmaxf(aL * yL + bL + (aF * yF + bF), 0.f);
    sx[it & 1][wid][lane] = x1;
    __syncthreads();
    float acc = b1v;
    const float4* xv = (const float4*)&sx[it & 1][wid][0];
#pragma unroll
    for (int k4 = 0; k4 < 16; ++k4) {
      const float4 xq = xv[k4];
      acc += w1r[4 * k4 + 0] * xq.x + w1r[4 * k4 + 1] * xq.y +
             w1r[4 * k4 + 2] * xq.z + w1r[4 * k4 + 3] * xq.w;
    }
    s1 += acc; q1 += acc * acc;
    z1[(size_t)p * 64 + lane] = acc;
  }
  __shared__ float red[4][64][2];
  red[wid][lane][0] = s1; red[wid][lane][1] = q1;
  __syncthreads();
  if (wid == 0) {
    float a0 = 0.f, a1v = 0.f;
    for (int w = 0; w < 4; ++w) { a0 += red[w][lane][0]; a1v += red[w][lane][1]; }
    atomicAdd(&stats[ST_SUM1 + lane], a0);
    atomicAdd(&stats[ST_SQ1 + lane], a1v);
  }
}

// ==================================================================
// 6) BN1+relu -> conv2 (128ch) + stats2; z2 written bf16 IN-PLACE over z1
// ==================================================================
__global__ __launch_bounds__(256, 2) void k6_kernel(
    float* __restrict__ z12, float* __restrict__ stats,
    const float* __restrict__ w2, const float* __restrict__ b2) {
  const int lane = threadIdx.x & 63, wid = threadIdx.x >> 6;
  const int wgid = blockIdx.x * 4 + wid;
  float w2a[64], w2b[64];
#pragma unroll
  for (int k = 0; k < 64; ++k) w2a[k] = w2[lane * 64 + k];
#pragma unroll
  for (int k = 0; k < 64; ++k) w2b[k] = w2[(lane + 64) * 64 + k];
  const float b2a = b2[lane], b2b = b2[lane + 64];
  const float a1 = stats[P_A1 + lane], b1p = stats[P_B1 + lane];
  float s0 = 0.f, q0 = 0.f, s1 = 0.f, q1 = 0.f;
  __shared__ __align__(16) float sx[2][4][64];
  __hip_bfloat16* zo = (__hip_bfloat16*)z12;
  for (int it = 0; it < 128; ++it) {
    const int p = it * 2048 + wgid;
    const float z = z12[(size_t)p * 64 + lane];
    const float x2 = fmaxf(a1 * z + b1p, 0.f);
    sx[it & 1][wid][lane] = x2;
    __syncthreads();
    float acc0 = b2a, acc1 = b2b;
    const float4* xv = (const float4*)&sx[it & 1][wid][0];
#pragma unroll
    for (int k4 = 0; k4 < 16; ++k4) {
      const float4 xq = xv[k4];
      acc0 += w2a[4 * k4] * xq.x + w2a[4 * k4 + 1] * xq.y + w2a[4 * k4 + 2] * xq.z + w2a[4 * k4 + 3] * xq.w;
      acc1 += w2b[4 * k4] * xq.x + w2b[4 * k4 + 1] * xq.y + w2b[4 * k4 + 2] * xq.z + w2b[4 * k4 + 3] * xq.w;
    }
    s0 += acc0; q0 += acc0 * acc0; s1 += acc1; q1 += acc1 * acc1;
    zo[(size_t)p * 128 + lane]      = __float2bfloat16(acc0);
    zo[(size_t)p * 128 + 64 + lane] = __float2bfloat16(acc1);
  }
  __shared__ float red[4][64][4];
  red[wid][lane][0] = s0; red[wid][lane][1] = q0;
  red[wid][lane][2] = s1; red[wid][lane][3] = q1;
  __syncthreads();
  if (wid == 0) {
    float t0 = 0.f, t1 = 0.f, t2 = 0.f, t3 = 0.f;
    for (int w = 0; w < 4; ++w) {
      t0 += red[w][lane][0]; t1 += red[w][lane][1];
      t2 += red[w][lane][2]; t3 += red[w][lane][3];
    }
    atomicAdd(&stats[ST_SUM2 + lane], t0);
    atomicAdd(&stats[ST_SQ2 + lane], t1);
    atomicAdd(&stats[ST_SUM2 + 64 + lane], t2);
    atomicAdd(&stats[ST_SQ2 + 64 + lane], t3);
  }
}

// ==================================================================
// 7) BN2 + relu + max over nsample, transposed write via LDS tile
//    block = (b, 64-m tile); out x shape (8,128,1024)
// ==================================================================
__global__ __launch_bounds__(256) void k7_kernel(const __hip_bfloat16* __restrict__ z2,
                                                 const float* __restrict__ stats,
                                                 float* __restrict__ out3) {
  const int b = blockIdx.x >> 4;
  const int mt = blockIdx.x & 15;
  const int t = threadIdx.x;
  const int o = t & 127, h = t >> 7;
  const float a = stats[P_A2 + o], bb = stats[P_B2 + o];
  __shared__ float tile[128][65];
  for (int j = 0; j < 32; ++j) {
    const int ml = h + 2 * j;
    const size_t rowbase = ((size_t)(b * 1024 + mt * 64 + ml)) * SS;
    float acc = -1e30f;
    for (int s = 0; s < SS; ++s) {
      const float v = __bfloat162float(z2[(rowbase + s) * 128 + o]);
      acc = fmaxf(acc, a * v + bb);
    }
    tile[o][ml] = fmaxf(acc, 0.f);                 // relu after max (monotone)
  }
  __syncthreads();
  const int r = t >> 1, c0 = (t & 1) * 32;
  float* dst = out3 + (size_t)b * 128 * 1024 + (size_t)r * 1024 + mt * 64 + c0;
  for (int j = 0; j < 32; ++j) dst[j] = tile[r][c0 + j];
}

// ==================================================================
extern "C" void kernel_launch(void* const* d_in, const int* in_sizes, int n_in,
                              void* d_out, int out_size, void* d_ws, size_t ws_size,
                              hipStream_t stream) {
  const float* center  = (const float*)d_in[0];
  const float* normal  = (const float*)d_in[1];
  const float* feature = (const float*)d_in[2];
  const float* w_l0 = (const float*)d_in[3];
  const float* b_l0 = (const float*)d_in[4];
  const float* g_l0 = (const float*)d_in[5];
  const float* be_l0 = (const float*)d_in[6];
  const float* w_f0 = (const float*)d_in[7];
  const float* b_f0 = (const float*)d_in[8];
  const float* g_f0 = (const float*)d_in[9];
  const float* be_f0 = (const float*)d_in[10];
  const float* w1 = (const float*)d_in[11];
  const float* b1 = (const float*)d_in[12];
  const float* g1 = (const float*)d_in[13];
  const float* be1 = (const float*)d_in[14];
  const float* w2 = (const float*)d_in[15];
  const float* b2 = (const float*)d_in[16];
  const float* g2 = (const float*)d_in[17];
  const float* be2 = (const float*)d_in[18];
  float* out = (float*)d_out;
  char* ws = (char*)d_ws;
  int*   fps_idx = (int*)(ws + OFF_FPS);
  float* stats   = (float*)(ws + OFF_STATS);
  float* x0      = (float*)(ws + OFF_X0);
  float* z1      = (float*)(ws + OFF_Z1);

  hipMemsetAsync(stats, 0, STATS_ZERO_BYTES, stream);
  hipLaunchKernelGGL(fps_kernel, dim3(8), dim3(512), 0, stream, center, fps_idx);
  hipLaunchKernelGGL(ball_gather_kernel, dim3(2048), dim3(256), 0, stream,
                     center, normal, feature, fps_idx, x0, out);
  hipLaunchKernelGGL(stats0_kernel, dim3(512), dim3(256), 0, stream,
                     x0, w_l0, b_l0, w_f0, b_f0, stats);
  hipLaunchKernelGGL(finalize0_kernel, dim3(1), dim3(128), 0, stream,
                     stats, g_l0, be_l0, g_f0, be_f0);
  hipLaunchKernelGGL(k5_kernel, dim3(512), dim3(256), 0, stream,
                     x0, z1, stats, w_l0, b_l0, w_f0, b_f0, w1, b1);
  hipLaunchKernelGGL(finalize1_kernel, dim3(1), dim3(64), 0, stream, stats, g1, be1);
  hipLaunchKernelGGL(k6_kernel, dim3(512), dim3(256), 0, stream, z1, stats, w2, b2);
  hipLaunchKernelGGL(finalize2_kernel, dim3(1), dim3(128), 0, stream, stats, g2, be2);
  hipLaunchKernelGGL(k7_kernel, dim3(128), dim3(256), 0, stream,
                     (const __hip_bfloat16*)z1, stats, out + 49152);
}

// Round 4
// 1428.463 us; speedup vs baseline: 1.2250x; 1.0524x over previous
//
#include <hip/hip_runtime.h>
#include <hip/hip_bf16.h>
#include <cstdint>
#include <cstddef>

// ---------------- problem constants ----------------
#define BB 8
#define NN 8192
#define MM 1024
#define SS 32
#define PTOT (BB*MM*SS)          // 262144
// threshold must match f32(0.2*0.2 computed in double) — NOT 0.2f*0.2f
__device__ __constant__ float kR2 = 0.039999999105930328f;

// ---------------- stats layout (float offsets in ws) ----------------
#define ST_SUM0L 0
#define ST_SQ0L  64
#define ST_SUM0F 128
#define ST_SQ0F  192
#define ST_SUM1  256
#define ST_SQ1   320
#define ST_SUM2  384
#define ST_SQ2   512
#define P_AL     640
#define P_BL     704
#define P_AF     768
#define P_BF     832
#define P_A1     896
#define P_B1     960
#define P_A2     1024
#define P_B2     1152
#define STATS_ZERO_BYTES (640*4)

// ws byte offsets
#define OFF_FPS   0u
#define OFF_STATS 32768u
#define OFF_X0    40960u
#define OFF_Z1    12623872u      // x0 ends at 40960 + 262144*48 = 12623872

typedef float v2f __attribute__((ext_vector_type(2)));

// rocPRIM-standard wave64 DPP reduction steps:
// row_shr:1 (0x111), row_shr:2 (0x112), row_shr:4 (0x114, bank 0xe),
// row_shr:8 (0x118, bank 0xc), row_bcast:15 (0x142, rows 0xa),
// row_bcast:31 (0x143, rows 0xc). Lane 63 ends with the full reduce.
// update_dpp(old=v, src=v, ...): masked/out-of-bounds lanes keep v.
#define DPP_FMAX(v, ctrl, rm, bm)                                          \
  v = fmaxf(v, __int_as_float(__builtin_amdgcn_update_dpp(                 \
      __float_as_int(v), __float_as_int(v), ctrl, rm, bm, false)));
#define DPP_UMIN(v, ctrl, rm, bm) {                                        \
  const unsigned _o = (unsigned)__builtin_amdgcn_update_dpp(               \
      (int)(v), (int)(v), ctrl, rm, bm, false);                            \
  v = (_o < v) ? _o : v; }

// ==================================================================
// 1) FPS v7: coords pinned in registers (R2), intra-wave reduce moved
//    from u64 shfl_xor butterfly (12 dependent ds_bpermute ~300cyc +
//    u64 cmp/select VALU) to DPP ops on the VALU pipe (~40cyc):
//      tree-max(16 temps) -> DPP f32 max -> readlane(63) = wave max
//      scan 16 temps vs wave max -> candidate point idx (lowest local)
//      DPP u32 min -> readlane(63) = wave argmax index
//    Tie semantics identical to the proven u64 key scheme (max value,
//    lowest point index). Cross-wave 8-key LDS stage unchanged.
//    Distance math: v2f ops end-to-end (elementwise_min keeps the
//    vector chain intact), per-element op order unchanged
//    (contract off: sub,mul,add,add,min) -> bit-identical d.
// ==================================================================
__global__ __launch_bounds__(512, 2) void fps_kernel(const float* __restrict__ center,
                                                     int* __restrict__ fps_idx) {
  const int b = blockIdx.x;
  const int t = threadIdx.x;               // 0..511
  const int lane = t & 63, wid = t >> 6;   // 8 waves
  const float* cb = center + (size_t)b * NN * 3;
  __shared__ __align__(16) float4 sc[NN];            // 128 KB centroid table
  __shared__ unsigned long long s_wkey[2][8];
  v2f X[8], Y[8], Z[8], T[8];
#pragma unroll
  for (int j = 0; j < 8; ++j) {
    const int p0 = ((2 * j) << 9) | t;
    const int p1 = ((2 * j + 1) << 9) | t;
    const float x0 = cb[p0 * 3 + 0], y0 = cb[p0 * 3 + 1], z0 = cb[p0 * 3 + 2];
    const float x1 = cb[p1 * 3 + 0], y1 = cb[p1 * 3 + 1], z1 = cb[p1 * 3 + 2];
    sc[p0] = make_float4(x0, y0, z0, 0.f);
    sc[p1] = make_float4(x1, y1, z1, 0.f);
    X[j] = (v2f){x0, x1}; Y[j] = (v2f){y0, y1}; Z[j] = (v2f){z0, z1};
    T[j] = (v2f){1e10f, 1e10f};
    // pin: asm-defined values cannot be rematerialized from memory
    asm volatile("" : "+v"(X[j]), "+v"(Y[j]), "+v"(Z[j]));
  }
  __syncthreads();
  int far = 0;
  for (int i = 0; i < MM; ++i) {
    if (t == 0) fps_idx[(b << 10) + i] = far;
    // centroid: uniform-address LDS broadcast read
    const float4 c = sc[__builtin_amdgcn_readfirstlane(far)];
    const v2f cx2 = (v2f){c.x, c.x};
    const v2f cy2 = (v2f){c.y, c.y};
    const v2f cz2 = (v2f){c.z, c.z};
    {
#pragma clang fp contract(off)
#pragma unroll
      for (int j = 0; j < 8; ++j) {
        const v2f dx = X[j] - cx2;
        const v2f dy = Y[j] - cy2;
        const v2f dz = Z[j] - cz2;
        v2f d = dx * dx;
        d = d + dy * dy;
        d = d + dz * dz;
        T[j] = __builtin_elementwise_min(T[j], d);
      }
    }
    // ---- tree-max of 16 temps (value only; exact, order-free) ----
    const v2f m0 = __builtin_elementwise_max(T[0], T[1]);
    const v2f m1 = __builtin_elementwise_max(T[2], T[3]);
    const v2f m2 = __builtin_elementwise_max(T[4], T[5]);
    const v2f m3 = __builtin_elementwise_max(T[6], T[7]);
    const v2f n0 = __builtin_elementwise_max(m0, m1);
    const v2f n1 = __builtin_elementwise_max(m2, m3);
    const v2f r  = __builtin_elementwise_max(n0, n1);
    float wv = fmaxf(r.x, r.y);
    // ---- wave max via DPP (VALU pipe, lane 63 = full max) ----
    DPP_FMAX(wv, 0x111, 0xf, 0xf)
    DPP_FMAX(wv, 0x112, 0xf, 0xf)
    DPP_FMAX(wv, 0x114, 0xf, 0xe)
    DPP_FMAX(wv, 0x118, 0xf, 0xc)
    DPP_FMAX(wv, 0x142, 0xa, 0xf)
    DPP_FMAX(wv, 0x143, 0xc, 0xf)
    const float wmax = __int_as_float(
        __builtin_amdgcn_readlane(__float_as_int(wv), 63));
    // ---- lowest point index achieving wmax (descending: low idx wins) ----
    unsigned cand = 0x7fffffffu;
#pragma unroll
    for (int j = 7; j >= 0; --j) {
      if (T[j].y == wmax) cand = (unsigned)(((2 * j + 1) << 9) | t);
      if (T[j].x == wmax) cand = (unsigned)(((2 * j) << 9) | t);
    }
    // ---- wave min-index via DPP ----
    DPP_UMIN(cand, 0x111, 0xf, 0xf)
    DPP_UMIN(cand, 0x112, 0xf, 0xf)
    DPP_UMIN(cand, 0x114, 0xf, 0xe)
    DPP_UMIN(cand, 0x118, 0xf, 0xc)
    DPP_UMIN(cand, 0x142, 0xa, 0xf)
    DPP_UMIN(cand, 0x143, 0xc, 0xf)
    const unsigned widx = (unsigned)__builtin_amdgcn_readlane((int)cand, 63);
    // ---- cross-wave stage: 8 u64 keys (max value, then lowest index) ----
    if (lane == 0)
      s_wkey[i & 1][wid] =
          ((unsigned long long)__float_as_uint(wmax) << 32) | (~widx);
    __syncthreads();
    const unsigned long long* sk = s_wkey[i & 1];
    unsigned long long best = sk[0];
#pragma unroll
    for (int w = 1; w < 8; ++w) { const unsigned long long o = sk[w]; best = (o > best) ? o : best; }
    far = (int)(~(unsigned)best);
  }
}

// ==================================================================
// 2) Ball query (first 32 smallest in-radius indices) + gather + concat
//    one wave per (b,m); also writes new_center/new_normal outputs
// ==================================================================
__global__ __launch_bounds__(256) void ball_gather_kernel(
    const float* __restrict__ center, const float* __restrict__ normal,
    const float* __restrict__ feature, const int* __restrict__ fps_idx,
    float* __restrict__ x0, float* __restrict__ out) {
  const int lane = threadIdx.x & 63;
  const int wq = (int)((blockIdx.x * blockDim.x + threadIdx.x) >> 6); // 0..8191
  const int b = wq >> 10, m = wq & 1023;
  const float* cb = center  + (size_t)b * NN * 3;
  const float* nb = normal  + (size_t)b * NN * 3;
  const float* fb = feature + (size_t)b * 6 * NN;
  const int pstar = fps_idx[(b << 10) + m];
  const float qx = cb[pstar * 3 + 0], qy = cb[pstar * 3 + 1], qz = cb[pstar * 3 + 2];
  if (lane < 3) {
    out[b * 3072 + lane * 1024 + m]         = cb[pstar * 3 + lane];   // new_center^T
    out[24576 + b * 3072 + lane * 1024 + m] = nb[pstar * 3 + lane];   // new_normal^T
  }
  const size_t pos_base = (size_t)((b << 10) + m) * SS;
  int total = 0;
  int first_p = -1;
  const float r2 = kR2;
  for (int base = 0; base < NN && total < SS; base += 64) {
    const int p = base + lane;
    const float ppx = cb[p * 3], ppy = cb[p * 3 + 1], ppz = cb[p * 3 + 2];
    const float dx = ppx - qx, dy = ppy - qy, dz = ppz - qz;
    float d2;
    {
#pragma clang fp contract(off)
      d2 = dx * dx;
      d2 = d2 + dy * dy;
      d2 = d2 + dz * dz;
    }
    const bool hit = d2 < r2;
    const unsigned long long msk = __ballot(hit);
    if (first_p < 0 && msk) first_p = base + (int)__builtin_ctzll(msk);
    const int rank = (int)__popcll(msk & ((1ull << lane) - 1ull));
    const int slot = total + rank;
    if (hit && slot < SS) {
      float4 v0, v1, v2;
      v0.x = dx; v0.y = dy; v0.z = dz;             // group_center - new_center
      v0.w = nb[p * 3 + 0];
      v1.x = nb[p * 3 + 1];
      v1.y = nb[p * 3 + 2];
      v1.z = fb[p];
      v1.w = fb[NN + p];
      v2.x = fb[2 * NN + p];
      v2.y = fb[3 * NN + p];
      v2.z = fb[4 * NN + p];
      v2.w = fb[5 * NN + p];
      float4* dst = (float4*)(x0 + (pos_base + (size_t)slot) * 12);
      dst[0] = v0; dst[1] = v1; dst[2] = v2;
    }
    total += (int)__popcll(msk);
  }
  if (total < SS) {                                // pad with first hit (ref semantics)
    if (first_p < 0) first_p = 0;
    const int p = first_p;
    const float ppx = cb[p * 3], ppy = cb[p * 3 + 1], ppz = cb[p * 3 + 2];
    float4 v0, v1, v2;
    v0.x = ppx - qx; v0.y = ppy - qy; v0.z = ppz - qz;
    v0.w = nb[p * 3 + 0]; v1.x = nb[p * 3 + 1]; v1.y = nb[p * 3 + 2];
    v1.z = fb[p]; v1.w = fb[NN + p];
    v2.x = fb[2 * NN + p]; v2.y = fb[3 * NN + p]; v2.z = fb[4 * NN + p]; v2.w = fb[5 * NN + p];
    for (int slot = total + lane; slot < SS; slot += 64) {
      float4* dst = (float4*)(x0 + (pos_base + (size_t)slot) * 12);
      dst[0] = v0; dst[1] = v1; dst[2] = v2;
    }
  }
}

// ==================================================================
// 3) stats for layer0 conv outputs (loc 64ch + ftr 64ch), lane = channel
// ==================================================================
__global__ __launch_bounds__(256) void stats0_kernel(
    const float* __restrict__ x0,
    const float* __restrict__ w_l0, const float* __restrict__ b_l0,
    const float* __restrict__ w_f0, const float* __restrict__ b_f0,
    float* __restrict__ stats) {
  const int lane = threadIdx.x & 63, wid = threadIdx.x >> 6;
  const int wgid = blockIdx.x * 4 + wid;           // 0..2047
  float wl[3], wf[9];
#pragma unroll
  for (int j = 0; j < 3; ++j) wl[j] = w_l0[lane * 3 + j];
#pragma unroll
  for (int j = 0; j < 9; ++j) wf[j] = w_f0[lane * 9 + j];
  const float bl = b_l0[lane], bf = b_f0[lane];
  float sL = 0.f, qL = 0.f, sF = 0.f, qF = 0.f;
  for (int it = 0; it < 128; ++it) {
    const int p = it * 2048 + wgid;
    const float4* row = (const float4*)(x0 + (size_t)p * 12);
    const float4 r0 = row[0], r1 = row[1], r2 = row[2];
    const float yL = bl + wl[0] * r0.x + wl[1] * r0.y + wl[2] * r0.z;
    const float yF = bf + wf[0] * r0.w + wf[1] * r1.x + wf[2] * r1.y + wf[3] * r1.z +
                     wf[4] * r1.w + wf[5] * r2.x + wf[6] * r2.y + wf[7] * r2.z + wf[8] * r2.w;
    sL += yL; qL += yL * yL; sF += yF; qF += yF * yF;
  }
  __shared__ float red[4][64][4];
  red[wid][lane][0] = sL; red[wid][lane][1] = qL;
  red[wid][lane][2] = sF; red[wid][lane][3] = qF;
  __syncthreads();
  if (wid == 0) {
    float a0 = 0.f, a1 = 0.f, a2 = 0.f, a3 = 0.f;
    for (int w = 0; w < 4; ++w) {
      a0 += red[w][lane][0]; a1 += red[w][lane][1];
      a2 += red[w][lane][2]; a3 += red[w][lane][3];
    }
    atomicAdd(&stats[ST_SUM0L + lane], a0);
    atomicAdd(&stats[ST_SQ0L + lane], a1);
    atomicAdd(&stats[ST_SUM0F + lane], a2);
    atomicAdd(&stats[ST_SQ0F + lane], a3);
  }
}

// ==================================================================
// finalize kernels: sums -> (a, b') with y_norm = a*y + b'
// ==================================================================
__global__ void finalize0_kernel(float* stats, const float* gl, const float* bel,
                                 const float* gf, const float* bef) {
  const int t = threadIdx.x;                        // 128
  const float invN = 1.0f / (float)PTOT;
  if (t < 64) {
    const float mean = stats[ST_SUM0L + t] * invN;
    const float var  = stats[ST_SQ0L + t] * invN - mean * mean;
    const float a = gl[t] / sqrtf(var + 1e-5f);
    stats[P_AL + t] = a;
    stats[P_BL + t] = bel[t] - a * mean;
  } else {
    const int c = t - 64;
    const float mean = stats[ST_SUM0F + c] * invN;
    const float var  = stats[ST_SQ0F + c] * invN - mean * mean;
    const float a = gf[c] / sqrtf(var + 1e-5f);
    stats[P_AF + c] = a;
    stats[P_BF + c] = bef[c] - a * mean;
  }
}
__global__ void finalize1_kernel(float* stats, const float* g, const float* be) {
  const int t = threadIdx.x;                        // 64
  const float invN = 1.0f / (float)PTOT;
  const float mean = stats[ST_SUM1 + t] * invN;
  const float var  = stats[ST_SQ1 + t] * invN - mean * mean;
  const float a = g[t] / sqrtf(var + 1e-5f);
  stats[P_A1 + t] = a;
  stats[P_B1 + t] = be[t] - a * mean;
}
__global__ void finalize2_kernel(float* stats, const float* g, const float* be) {
  const int t = threadIdx.x;                        // 128
  const float invN = 1.0f / (float)PTOT;
  const float mean = stats[ST_SUM2 + t] * invN;
  const float var  = stats[ST_SQ2 + t] * invN - mean * mean;
  const float a = g[t] / sqrtf(var + 1e-5f);
  stats[P_A2 + t] = a;
  stats[P_B2 + t] = be[t] - a * mean;
}

// ==================================================================
// 5) conv0 + BN0 + relu  ->  conv1 (z1 stored f32) + stats1
//    lane = output channel; per-position x1 broadcast via wave-private LDS
// ==================================================================
__global__ __launch_bounds__(256) void k5_kernel(
    const float* __restrict__ x0, float* __restrict__ z1,
    float* __restrict__ stats,
    const float* __restrict__ w_l0, const float* __restrict__ b_l0,
    const float* __restrict__ w_f0, const float* __restrict__ b_f0,
    const float* __restrict__ w1, const float* __restrict__ b1) {
  const int lane = threadIdx.x & 63, wid = threadIdx.x >> 6;
  const int wgid = blockIdx.x * 4 + wid;
  float wl[3], wf[9], w1r[64];
#pragma unroll
  for (int j = 0; j < 3; ++j) wl[j] = w_l0[lane * 3 + j];
#pragma unroll
  for (int j = 0; j < 9; ++j) wf[j] = w_f0[lane * 9 + j];
#pragma unroll
  for (int k = 0; k < 64; ++k) w1r[k] = w1[lane * 64 + k];
  const float bl = b_l0[lane], bf = b_f0[lane], b1v = b1[lane];
  const float aL = stats[P_AL + lane], bL = stats[P_BL + lane];
  const float aF = stats[P_AF + lane], bF = stats[P_BF + lane];
  float s1 = 0.f, q1 = 0.f;
  __shared__ __align__(16) float sx[2][4][64];
  for (int it = 0; it < 128; ++it) {
    const int p = it * 2048 + wgid;
    const float4* row = (const float4*)(x0 + (size_t)p * 12);
    const float4 r0 = row[0], r1 = row[1], r2 = row[2];
    const float yL = bl + wl[0] * r0.x + wl[1] * r0.y + wl[2] * r0.z;
    const float yF = bf + wf[0] * r0.w + wf[1] * r1.x + wf[2] * r1.y + wf[3] * r1.z +
                     wf[4] * r1.w + wf[5] * r2.x + wf[6] * r2.y + wf[7] * r2.z + wf[8] * r2.w;
    const float x1 = fmaxf(aL * yL + bL + (aF * yF + bF), 0.f);
    sx[it & 1][wid][lane] = x1;
    __syncthreads();
    float acc = b1v;
    const float4* xv = (const float4*)&sx[it & 1][wid][0];
#pragma unroll
    for (int k4 = 0; k4 < 16; ++k4) {
      const float4 xq = xv[k4];
      acc += w1r[4 * k4 + 0] * xq.x + w1r[4 * k4 + 1] * xq.y +
             w1r[4 * k4 + 2] * xq.z + w1r[4 * k4 + 3] * xq.w;
    }
    s1 += acc; q1 += acc * acc;
    z1[(size_t)p * 64 + lane] = acc;
  }
  __shared__ float red[4][64][2];
  red[wid][lane][0] = s1; red[wid][lane][1] = q1;
  __syncthreads();
  if (wid == 0) {
    float a0 = 0.f, a1v = 0.f;
    for (int w = 0; w < 4; ++w) { a0 += red[w][lane][0]; a1v += red[w][lane][1]; }
    atomicAdd(&stats[ST_SUM1 + lane], a0);
    atomicAdd(&stats[ST_SQ1 + lane], a1v);
  }
}

// ==================================================================
// 6) BN1+relu -> conv2 (128ch) + stats2; z2 written bf16 IN-PLACE over z1
// ==================================================================
__global__ __launch_bounds__(256, 2) void k6_kernel(
    float* __restrict__ z12, float* __restrict__ stats,
    const float* __restrict__ w2, const float* __restrict__ b2) {
  const int lane = threadIdx.x & 63, wid = threadIdx.x >> 6;
  const int wgid = blockIdx.x * 4 + wid;
  float w2a[64], w2b[64];
#pragma unroll
  for (int k = 0; k < 64; ++k) w2a[k] = w2[lane * 64 + k];
#pragma unroll
  for (int k = 0; k < 64; ++k) w2b[k] = w2[(lane + 64) * 64 + k];
  const float b2a = b2[lane], b2b = b2[lane + 64];
  const float a1 = stats[P_A1 + lane], b1p = stats[P_B1 + lane];
  float s0 = 0.f, q0 = 0.f, s1 = 0.f, q1 = 0.f;
  __shared__ __align__(16) float sx[2][4][64];
  __hip_bfloat16* zo = (__hip_bfloat16*)z12;
  for (int it = 0; it < 128; ++it) {
    const int p = it * 2048 + wgid;
    const float z = z12[(size_t)p * 64 + lane];
    const float x2 = fmaxf(a1 * z + b1p, 0.f);
    sx[it & 1][wid][lane] = x2;
    __syncthreads();
    float acc0 = b2a, acc1 = b2b;
    const float4* xv = (const float4*)&sx[it & 1][wid][0];
#pragma unroll
    for (int k4 = 0; k4 < 16; ++k4) {
      const float4 xq = xv[k4];
      acc0 += w2a[4 * k4] * xq.x + w2a[4 * k4 + 1] * xq.y + w2a[4 * k4 + 2] * xq.z + w2a[4 * k4 + 3] * xq.w;
      acc1 += w2b[4 * k4] * xq.x + w2b[4 * k4 + 1] * xq.y + w2b[4 * k4 + 2] * xq.z + w2b[4 * k4 + 3] * xq.w;
    }
    s0 += acc0; q0 += acc0 * acc0; s1 += acc1; q1 += acc1 * acc1;
    zo[(size_t)p * 128 + lane]      = __float2bfloat16(acc0);
    zo[(size_t)p * 128 + 64 + lane] = __float2bfloat16(acc1);
  }
  __shared__ float red[4][64][4];
  red[wid][lane][0] = s0; red[wid][lane][1] = q0;
  red[wid][lane][2] = s1; red[wid][lane][3] = q1;
  __syncthreads();
  if (wid == 0) {
    float t0 = 0.f, t1 = 0.f, t2 = 0.f, t3 = 0.f;
    for (int w = 0; w < 4; ++w) {
      t0 += red[w][lane][0]; t1 += red[w][lane][1];
      t2 += red[w][lane][2]; t3 += red[w][lane][3];
    }
    atomicAdd(&stats[ST_SUM2 + lane], t0);
    atomicAdd(&stats[ST_SQ2 + lane], t1);
    atomicAdd(&stats[ST_SUM2 + 64 + lane], t2);
    atomicAdd(&stats[ST_SQ2 + 64 + lane], t3);
  }
}

// ==================================================================
// 7) BN2 + relu + max over nsample, transposed write via LDS tile
//    block = (b, 64-m tile); out x shape (8,128,1024)
// ==================================================================
__global__ __launch_bounds__(256) void k7_kernel(const __hip_bfloat16* __restrict__ z2,
                                                 const float* __restrict__ stats,
                                                 float* __restrict__ out3) {
  const int b = blockIdx.x >> 4;
  const int mt = blockIdx.x & 15;
  const int t = threadIdx.x;
  const int o = t & 127, h = t >> 7;
  const float a = stats[P_A2 + o], bb = stats[P_B2 + o];
  __shared__ float tile[128][65];
  for (int j = 0; j < 32; ++j) {
    const int ml = h + 2 * j;
    const size_t rowbase = ((size_t)(b * 1024 + mt * 64 + ml)) * SS;
    float acc = -1e30f;
    for (int s = 0; s < SS; ++s) {
      const float v = __bfloat162float(z2[(rowbase + s) * 128 + o]);
      acc = fmaxf(acc, a * v + bb);
    }
    tile[o][ml] = fmaxf(acc, 0.f);                 // relu after max (monotone)
  }
  __syncthreads();
  const int r = t >> 1, c0 = (t & 1) * 32;
  float* dst = out3 + (size_t)b * 128 * 1024 + (size_t)r * 1024 + mt * 64 + c0;
  for (int j = 0; j < 32; ++j) dst[j] = tile[r][c0 + j];
}

// ==================================================================
extern "C" void kernel_launch(void* const* d_in, const int* in_sizes, int n_in,
                              void* d_out, int out_size, void* d_ws, size_t ws_size,
                              hipStream_t stream) {
  const float* center  = (const float*)d_in[0];
  const float* normal  = (const float*)d_in[1];
  const float* feature = (const float*)d_in[2];
  const float* w_l0 = (const float*)d_in[3];
  const float* b_l0 = (const float*)d_in[4];
  const float* g_l0 = (const float*)d_in[5];
  const float* be_l0 = (const float*)d_in[6];
  const float* w_f0 = (const float*)d_in[7];
  const float* b_f0 = (const float*)d_in[8];
  const float* g_f0 = (const float*)d_in[9];
  const float* be_f0 = (const float*)d_in[10];
  const float* w1 = (const float*)d_in[11];
  const float* b1 = (const float*)d_in[12];
  const float* g1 = (const float*)d_in[13];
  const float* be1 = (const float*)d_in[14];
  const float* w2 = (const float*)d_in[15];
  const float* b2 = (const float*)d_in[16];
  const float* g2 = (const float*)d_in[17];
  const float* be2 = (const float*)d_in[18];
  float* out = (float*)d_out;
  char* ws = (char*)d_ws;
  int*   fps_idx = (int*)(ws + OFF_FPS);
  float* stats   = (float*)(ws + OFF_STATS);
  float* x0      = (float*)(ws + OFF_X0);
  float* z1      = (float*)(ws + OFF_Z1);

  hipMemsetAsync(stats, 0, STATS_ZERO_BYTES, stream);
  hipLaunchKernelGGL(fps_kernel, dim3(8), dim3(512), 0, stream, center, fps_idx);
  hipLaunchKernelGGL(ball_gather_kernel, dim3(2048), dim3(256), 0, stream,
                     center, normal, feature, fps_idx, x0, out);
  hipLaunchKernelGGL(stats0_kernel, dim3(512), dim3(256), 0, stream,
                     x0, w_l0, b_l0, w_f0, b_f0, stats);
  hipLaunchKernelGGL(finalize0_kernel, dim3(1), dim3(128), 0, stream,
                     stats, g_l0, be_l0, g_f0, be_f0);
  hipLaunchKernelGGL(k5_kernel, dim3(512), dim3(256), 0, stream,
                     x0, z1, stats, w_l0, b_l0, w_f0, b_f0, w1, b1);
  hipLaunchKernelGGL(finalize1_kernel, dim3(1), dim3(64), 0, stream, stats, g1, be1);
  hipLaunchKernelGGL(k6_kernel, dim3(512), dim3(256), 0, stream, z1, stats, w2, b2);
  hipLaunchKernelGGL(finalize2_kernel, dim3(1), dim3(128), 0, stream, stats, g2, be2);
  hipLaunchKernelGGL(k7_kernel, dim3(128), dim3(256), 0, stream,
                     (const __hip_bfloat16*)z1, stats, out + 49152);
}

// Round 5
// 1391.092 us; speedup vs baseline: 1.2579x; 1.0269x over previous
//
#include <hip/hip_runtime.h>
#include <hip/hip_bf16.h>
#include <cstdint>
#include <cstddef>

// ---------------- problem constants ----------------
#define BB 8
#define NN 8192
#define MM 1024
#define SS 32
#define PTOT (BB*MM*SS)          // 262144
// threshold must match f32(0.2*0.2 computed in double) — NOT 0.2f*0.2f
__device__ __constant__ float kR2 = 0.039999999105930328f;

// ---------------- stats layout (float offsets in ws) ----------------
#define ST_SUM0L 0
#define ST_SQ0L  64
#define ST_SUM0F 128
#define ST_SQ0F  192
#define ST_SUM1  256
#define ST_SQ1   320
#define ST_SUM2  384
#define ST_SQ2   512
#define P_AL     640
#define P_BL     704
#define P_AF     768
#define P_BF     832
#define P_A1     896
#define P_B1     960
#define P_A2     1024
#define P_B2     1152
#define STATS_ZERO_BYTES (640*4)

// ws byte offsets
#define OFF_FPS   0u
#define OFF_STATS 32768u
#define OFF_X0    40960u
#define OFF_Z1    12623872u      // x0 ends at 40960 + 262144*48 = 12623872

typedef float v2f __attribute__((ext_vector_type(2)));

// rocPRIM-standard wave64 DPP reduction steps:
// row_shr:1 (0x111), row_shr:2 (0x112), row_shr:4 (0x114, bank 0xe),
// row_shr:8 (0x118, bank 0xc), row_bcast:15 (0x142, rows 0xa),
// row_bcast:31 (0x143, rows 0xc). Lane 63 ends with the full reduce.
#define DPP_FMAX(v, ctrl, rm, bm)                                          \
  v = fmaxf(v, __int_as_float(__builtin_amdgcn_update_dpp(                 \
      __float_as_int(v), __float_as_int(v), ctrl, rm, bm, false)));
#define DPP_UMIN(v, ctrl, rm, bm) {                                        \
  const unsigned _o = (unsigned)__builtin_amdgcn_update_dpp(               \
      (int)(v), (int)(v), ctrl, rm, bm, false);                            \
  v = (_o < v) ? _o : v; }

// ==================================================================
// 1) FPS v8: 256 threads (4 waves, 1 wave/SIMD), 32 pts/thread pinned
//    in registers. R3 showed ~2x the modeled VALU cycles — testing the
//    "per-wave overhead" hypothesis: per-point work is wave-count-
//    invariant per SIMD, per-wave work (DPP chains, key stage, loop
//    bookkeeping, the unexplained mass) halves with half the waves.
//    Point mapping p=(k<<8)|t, k in [0,32), t in [0,256): candidate
//    pack (k<<8)|t == p keeps min == lowest global point index; scan
//    descends k (.y then .x) so lowest k assigned last — np.argmax tie
//    semantics preserved exactly. Distance op order unchanged
//    (contract off: sub,mul,mul,add,mul,add,min per element).
// ==================================================================
__global__ __launch_bounds__(256, 1) void fps_kernel(const float* __restrict__ center,
                                                     int* __restrict__ fps_idx) {
  const int b = blockIdx.x;
  const int t = threadIdx.x;               // 0..255
  const int lane = t & 63, wid = t >> 6;   // 4 waves
  const float* cb = center + (size_t)b * NN * 3;
  __shared__ __align__(16) float4 sc[NN];            // 128 KB centroid table
  __shared__ unsigned long long s_wkey[2][4];
  v2f X[16], Y[16], Z[16], T[16];
#pragma unroll
  for (int j = 0; j < 16; ++j) {
    const int p0 = ((2 * j) << 8) | t;
    const int p1 = ((2 * j + 1) << 8) | t;
    const float x0 = cb[p0 * 3 + 0], y0 = cb[p0 * 3 + 1], z0 = cb[p0 * 3 + 2];
    const float x1 = cb[p1 * 3 + 0], y1 = cb[p1 * 3 + 1], z1 = cb[p1 * 3 + 2];
    sc[p0] = make_float4(x0, y0, z0, 0.f);
    sc[p1] = make_float4(x1, y1, z1, 0.f);
    X[j] = (v2f){x0, x1}; Y[j] = (v2f){y0, y1}; Z[j] = (v2f){z0, z1};
    T[j] = (v2f){1e10f, 1e10f};
    // pin: asm-defined values cannot be rematerialized from memory
    asm volatile("" : "+v"(X[j]), "+v"(Y[j]), "+v"(Z[j]));
  }
  __syncthreads();
  int far = 0;
  for (int i = 0; i < MM; ++i) {
    if (t == 0) fps_idx[(b << 10) + i] = far;
    // centroid: uniform-address LDS broadcast read
    const float4 c = sc[__builtin_amdgcn_readfirstlane(far)];
    const v2f cx2 = (v2f){c.x, c.x};
    const v2f cy2 = (v2f){c.y, c.y};
    const v2f cz2 = (v2f){c.z, c.z};
    {
#pragma clang fp contract(off)
#pragma unroll
      for (int j = 0; j < 16; ++j) {
        const v2f dx = X[j] - cx2;
        const v2f dy = Y[j] - cy2;
        const v2f dz = Z[j] - cz2;
        v2f d = dx * dx;
        d = d + dy * dy;
        d = d + dz * dz;
        T[j] = __builtin_elementwise_min(T[j], d);
      }
    }
    // ---- tree-max of 32 temps (value only; exact, order-free) ----
    v2f m[8];
#pragma unroll
    for (int j = 0; j < 8; ++j) m[j] = __builtin_elementwise_max(T[2 * j], T[2 * j + 1]);
    const v2f n0 = __builtin_elementwise_max(m[0], m[1]);
    const v2f n1 = __builtin_elementwise_max(m[2], m[3]);
    const v2f n2 = __builtin_elementwise_max(m[4], m[5]);
    const v2f n3 = __builtin_elementwise_max(m[6], m[7]);
    const v2f q0 = __builtin_elementwise_max(n0, n1);
    const v2f q1 = __builtin_elementwise_max(n2, n3);
    const v2f r  = __builtin_elementwise_max(q0, q1);
    float wv = fmaxf(r.x, r.y);
    // ---- wave max via DPP (VALU pipe, lane 63 = full max) ----
    DPP_FMAX(wv, 0x111, 0xf, 0xf)
    DPP_FMAX(wv, 0x112, 0xf, 0xf)
    DPP_FMAX(wv, 0x114, 0xf, 0xe)
    DPP_FMAX(wv, 0x118, 0xf, 0xc)
    DPP_FMAX(wv, 0x142, 0xa, 0xf)
    DPP_FMAX(wv, 0x143, 0xc, 0xf)
    const float wmax = __int_as_float(
        __builtin_amdgcn_readlane(__float_as_int(wv), 63));
    // ---- lowest point index achieving wmax (descending: low idx wins) ----
    unsigned cand = 0x7fffffffu;
#pragma unroll
    for (int j = 15; j >= 0; --j) {
      if (T[j].y == wmax) cand = (unsigned)(((2 * j + 1) << 8) | t);
      if (T[j].x == wmax) cand = (unsigned)(((2 * j) << 8) | t);
    }
    // ---- wave min-index via DPP ----
    DPP_UMIN(cand, 0x111, 0xf, 0xf)
    DPP_UMIN(cand, 0x112, 0xf, 0xf)
    DPP_UMIN(cand, 0x114, 0xf, 0xe)
    DPP_UMIN(cand, 0x118, 0xf, 0xc)
    DPP_UMIN(cand, 0x142, 0xa, 0xf)
    DPP_UMIN(cand, 0x143, 0xc, 0xf)
    const unsigned widx = (unsigned)__builtin_amdgcn_readlane((int)cand, 63);
    // ---- cross-wave stage: 4 u64 keys (max value, then lowest index) ----
    if (lane == 0)
      s_wkey[i & 1][wid] =
          ((unsigned long long)__float_as_uint(wmax) << 32) | (~widx);
    __syncthreads();
    const unsigned long long* sk = s_wkey[i & 1];
    const unsigned long long k0 = sk[0], k1 = sk[1], k2 = sk[2], k3 = sk[3];
    const unsigned long long h0 = (k1 > k0) ? k1 : k0;
    const unsigned long long h1 = (k3 > k2) ? k3 : k2;
    const unsigned long long best = (h1 > h0) ? h1 : h0;
    far = (int)(~(unsigned)best);
  }
}

// ==================================================================
// 2) Ball query (first 32 smallest in-radius indices) + gather + concat
//    one wave per (b,m); also writes new_center/new_normal outputs
// ==================================================================
__global__ __launch_bounds__(256) void ball_gather_kernel(
    const float* __restrict__ center, const float* __restrict__ normal,
    const float* __restrict__ feature, const int* __restrict__ fps_idx,
    float* __restrict__ x0, float* __restrict__ out) {
  const int lane = threadIdx.x & 63;
  const int wq = (int)((blockIdx.x * blockDim.x + threadIdx.x) >> 6); // 0..8191
  const int b = wq >> 10, m = wq & 1023;
  const float* cb = center  + (size_t)b * NN * 3;
  const float* nb = normal  + (size_t)b * NN * 3;
  const float* fb = feature + (size_t)b * 6 * NN;
  const int pstar = fps_idx[(b << 10) + m];
  const float qx = cb[pstar * 3 + 0], qy = cb[pstar * 3 + 1], qz = cb[pstar * 3 + 2];
  if (lane < 3) {
    out[b * 3072 + lane * 1024 + m]         = cb[pstar * 3 + lane];   // new_center^T
    out[24576 + b * 3072 + lane * 1024 + m] = nb[pstar * 3 + lane];   // new_normal^T
  }
  const size_t pos_base = (size_t)((b << 10) + m) * SS;
  int total = 0;
  int first_p = -1;
  const float r2 = kR2;
  for (int base = 0; base < NN && total < SS; base += 64) {
    const int p = base + lane;
    const float ppx = cb[p * 3], ppy = cb[p * 3 + 1], ppz = cb[p * 3 + 2];
    const float dx = ppx - qx, dy = ppy - qy, dz = ppz - qz;
    float d2;
    {
#pragma clang fp contract(off)
      d2 = dx * dx;
      d2 = d2 + dy * dy;
      d2 = d2 + dz * dz;
    }
    const bool hit = d2 < r2;
    const unsigned long long msk = __ballot(hit);
    if (first_p < 0 && msk) first_p = base + (int)__builtin_ctzll(msk);
    const int rank = (int)__popcll(msk & ((1ull << lane) - 1ull));
    const int slot = total + rank;
    if (hit && slot < SS) {
      float4 v0, v1, v2;
      v0.x = dx; v0.y = dy; v0.z = dz;             // group_center - new_center
      v0.w = nb[p * 3 + 0];
      v1.x = nb[p * 3 + 1];
      v1.y = nb[p * 3 + 2];
      v1.z = fb[p];
      v1.w = fb[NN + p];
      v2.x = fb[2 * NN + p];
      v2.y = fb[3 * NN + p];
      v2.z = fb[4 * NN + p];
      v2.w = fb[5 * NN + p];
      float4* dst = (float4*)(x0 + (pos_base + (size_t)slot) * 12);
      dst[0] = v0; dst[1] = v1; dst[2] = v2;
    }
    total += (int)__popcll(msk);
  }
  if (total < SS) {                                // pad with first hit (ref semantics)
    if (first_p < 0) first_p = 0;
    const int p = first_p;
    const float ppx = cb[p * 3], ppy = cb[p * 3 + 1], ppz = cb[p * 3 + 2];
    float4 v0, v1, v2;
    v0.x = ppx - qx; v0.y = ppy - qy; v0.z = ppz - qz;
    v0.w = nb[p * 3 + 0]; v1.x = nb[p * 3 + 1]; v1.y = nb[p * 3 + 2];
    v1.z = fb[p]; v1.w = fb[NN + p];
    v2.x = fb[2 * NN + p]; v2.y = fb[3 * NN + p]; v2.z = fb[4 * NN + p]; v2.w = fb[5 * NN + p];
    for (int slot = total + lane; slot < SS; slot += 64) {
      float4* dst = (float4*)(x0 + (pos_base + (size_t)slot) * 12);
      dst[0] = v0; dst[1] = v1; dst[2] = v2;
    }
  }
}

// ==================================================================
// 3) stats for layer0 conv outputs (loc 64ch + ftr 64ch), lane = channel
// ==================================================================
__global__ __launch_bounds__(256) void stats0_kernel(
    const float* __restrict__ x0,
    const float* __restrict__ w_l0, const float* __restrict__ b_l0,
    const float* __restrict__ w_f0, const float* __restrict__ b_f0,
    float* __restrict__ stats) {
  const int lane = threadIdx.x & 63, wid = threadIdx.x >> 6;
  const int wgid = blockIdx.x * 4 + wid;           // 0..2047
  float wl[3], wf[9];
#pragma unroll
  for (int j = 0; j < 3; ++j) wl[j] = w_l0[lane * 3 + j];
#pragma unroll
  for (int j = 0; j < 9; ++j) wf[j] = w_f0[lane * 9 + j];
  const float bl = b_l0[lane], bf = b_f0[lane];
  float sL = 0.f, qL = 0.f, sF = 0.f, qF = 0.f;
  for (int it = 0; it < 128; ++it) {
    const int p = it * 2048 + wgid;
    const float4* row = (const float4*)(x0 + (size_t)p * 12);
    const float4 r0 = row[0], r1 = row[1], r2 = row[2];
    const float yL = bl + wl[0] * r0.x + wl[1] * r0.y + wl[2] * r0.z;
    const float yF = bf + wf[0] * r0.w + wf[1] * r1.x + wf[2] * r1.y + wf[3] * r1.z +
                     wf[4] * r1.w + wf[5] * r2.x + wf[6] * r2.y + wf[7] * r2.z + wf[8] * r2.w;
    sL += yL; qL += yL * yL; sF += yF; qF += yF * yF;
  }
  __shared__ float red[4][64][4];
  red[wid][lane][0] = sL; red[wid][lane][1] = qL;
  red[wid][lane][2] = sF; red[wid][lane][3] = qF;
  __syncthreads();
  if (wid == 0) {
    float a0 = 0.f, a1 = 0.f, a2 = 0.f, a3 = 0.f;
    for (int w = 0; w < 4; ++w) {
      a0 += red[w][lane][0]; a1 += red[w][lane][1];
      a2 += red[w][lane][2]; a3 += red[w][lane][3];
    }
    atomicAdd(&stats[ST_SUM0L + lane], a0);
    atomicAdd(&stats[ST_SQ0L + lane], a1);
    atomicAdd(&stats[ST_SUM0F + lane], a2);
    atomicAdd(&stats[ST_SQ0F + lane], a3);
  }
}

// ==================================================================
// finalize kernels: sums -> (a, b') with y_norm = a*y + b'
// ==================================================================
__global__ void finalize0_kernel(float* stats, const float* gl, const float* bel,
                                 const float* gf, const float* bef) {
  const int t = threadIdx.x;                        // 128
  const float invN = 1.0f / (float)PTOT;
  if (t < 64) {
    const float mean = stats[ST_SUM0L + t] * invN;
    const float var  = stats[ST_SQ0L + t] * invN - mean * mean;
    const float a = gl[t] / sqrtf(var + 1e-5f);
    stats[P_AL + t] = a;
    stats[P_BL + t] = bel[t] - a * mean;
  } else {
    const int c = t - 64;
    const float mean = stats[ST_SUM0F + c] * invN;
    const float var  = stats[ST_SQ0F + c] * invN - mean * mean;
    const float a = gf[c] / sqrtf(var + 1e-5f);
    stats[P_AF + c] = a;
    stats[P_BF + c] = bef[c] - a * mean;
  }
}
__global__ void finalize1_kernel(float* stats, const float* g, const float* be) {
  const int t = threadIdx.x;                        // 64
  const float invN = 1.0f / (float)PTOT;
  const float mean = stats[ST_SUM1 + t] * invN;
  const float var  = stats[ST_SQ1 + t] * invN - mean * mean;
  const float a = g[t] / sqrtf(var + 1e-5f);
  stats[P_A1 + t] = a;
  stats[P_B1 + t] = be[t] - a * mean;
}
__global__ void finalize2_kernel(float* stats, const float* g, const float* be) {
  const int t = threadIdx.x;                        // 128
  const float invN = 1.0f / (float)PTOT;
  const float mean = stats[ST_SUM2 + t] * invN;
  const float var  = stats[ST_SQ2 + t] * invN - mean * mean;
  const float a = g[t] / sqrtf(var + 1e-5f);
  stats[P_A2 + t] = a;
  stats[P_B2 + t] = be[t] - a * mean;
}

// ==================================================================
// 5) conv0 + BN0 + relu  ->  conv1 (z1 stored f32) + stats1
//    lane = output channel; per-position x1 broadcast via wave-private LDS
// ==================================================================
__global__ __launch_bounds__(256) void k5_kernel(
    const float* __restrict__ x0, float* __restrict__ z1,
    float* __restrict__ stats,
    const float* __restrict__ w_l0, const float* __restrict__ b_l0,
    const float* __restrict__ w_f0, const float* __restrict__ b_f0,
    const float* __restrict__ w1, const float* __restrict__ b1) {
  const int lane = threadIdx.x & 63, wid = threadIdx.x >> 6;
  const int wgid = blockIdx.x * 4 + wid;
  float wl[3], wf[9], w1r[64];
#pragma unroll
  for (int j = 0; j < 3; ++j) wl[j] = w_l0[lane * 3 + j];
#pragma unroll
  for (int j = 0; j < 9; ++j) wf[j] = w_f0[lane * 9 + j];
#pragma unroll
  for (int k = 0; k < 64; ++k) w1r[k] = w1[lane * 64 + k];
  const float bl = b_l0[lane], bf = b_f0[lane], b1v = b1[lane];
  const float aL = stats[P_AL + lane], bL = stats[P_BL + lane];
  const float aF = stats[P_AF + lane], bF = stats[P_BF + lane];
  float s1 = 0.f, q1 = 0.f;
  __shared__ __align__(16) float sx[2][4][64];
  for (int it = 0; it < 128; ++it) {
    const int p = it * 2048 + wgid;
    const float4* row = (const float4*)(x0 + (size_t)p * 12);
    const float4 r0 = row[0], r1 = row[1], r2 = row[2];
    const float yL = bl + wl[0] * r0.x + wl[1] * r0.y + wl[2] * r0.z;
    const float yF = bf + wf[0] * r0.w + wf[1] * r1.x + wf[2] * r1.y + wf[3] * r1.z +
                     wf[4] * r1.w + wf[5] * r2.x + wf[6] * r2.y + wf[7] * r2.z + wf[8] * r2.w;
    const float x1 = fmaxf(aL * yL + bL + (aF * yF + bF), 0.f);
    sx[it & 1][wid][lane] = x1;
    __syncthreads();
    float acc = b1v;
    const float4* xv = (const float4*)&sx[it & 1][wid][0];
#pragma unroll
    for (int k4 = 0; k4 < 16; ++k4) {
      const float4 xq = xv[k4];
      acc += w1r[4 * k4 + 0] * xq.x + w1r[4 * k4 + 1] * xq.y +
             w1r[4 * k4 + 2] * xq.z + w1r[4 * k4 + 3] * xq.w;
    }
    s1 += acc; q1 += acc * acc;
    z1[(size_t)p * 64 + lane] = acc;
  }
  __shared__ float red[4][64][2];
  red[wid][lane][0] = s1; red[wid][lane][1] = q1;
  __syncthreads();
  if (wid == 0) {
    float a0 = 0.f, a1v = 0.f;
    for (int w = 0; w < 4; ++w) { a0 += red[w][lane][0]; a1v += red[w][lane][1]; }
    atomicAdd(&stats[ST_SUM1 + lane], a0);
    atomicAdd(&stats[ST_SQ1 + lane], a1v);
  }
}

// ==================================================================
// 6) BN1+relu -> conv2 (128ch) + stats2; z2 written bf16 IN-PLACE over z1
// ==================================================================
__global__ __launch_bounds__(256, 2) void k6_kernel(
    float* __restrict__ z12, float* __restrict__ stats,
    const float* __restrict__ w2, const float* __restrict__ b2) {
  const int lane = threadIdx.x & 63, wid = threadIdx.x >> 6;
  const int wgid = blockIdx.x * 4 + wid;
  float w2a[64], w2b[64];
#pragma unroll
  for (int k = 0; k < 64; ++k) w2a[k] = w2[lane * 64 + k];
#pragma unroll
  for (int k = 0; k < 64; ++k) w2b[k] = w2[(lane + 64) * 64 + k];
  const float b2a = b2[lane], b2b = b2[lane + 64];
  const float a1 = stats[P_A1 + lane], b1p = stats[P_B1 + lane];
  float s0 = 0.f, q0 = 0.f, s1 = 0.f, q1 = 0.f;
  __shared__ __align__(16) float sx[2][4][64];
  __hip_bfloat16* zo = (__hip_bfloat16*)z12;
  for (int it = 0; it < 128; ++it) {
    const int p = it * 2048 + wgid;
    const float z = z12[(size_t)p * 64 + lane];
    const float x2 = fmaxf(a1 * z + b1p, 0.f);
    sx[it & 1][wid][lane] = x2;
    __syncthreads();
    float acc0 = b2a, acc1 = b2b;
    const float4* xv = (const float4*)&sx[it & 1][wid][0];
#pragma unroll
    for (int k4 = 0; k4 < 16; ++k4) {
      const float4 xq = xv[k4];
      acc0 += w2a[4 * k4] * xq.x + w2a[4 * k4 + 1] * xq.y + w2a[4 * k4 + 2] * xq.z + w2a[4 * k4 + 3] * xq.w;
      acc1 += w2b[4 * k4] * xq.x + w2b[4 * k4 + 1] * xq.y + w2b[4 * k4 + 2] * xq.z + w2b[4 * k4 + 3] * xq.w;
    }
    s0 += acc0; q0 += acc0 * acc0; s1 += acc1; q1 += acc1 * acc1;
    zo[(size_t)p * 128 + lane]      = __float2bfloat16(acc0);
    zo[(size_t)p * 128 + 64 + lane] = __float2bfloat16(acc1);
  }
  __shared__ float red[4][64][4];
  red[wid][lane][0] = s0; red[wid][lane][1] = q0;
  red[wid][lane][2] = s1; red[wid][lane][3] = q1;
  __syncthreads();
  if (wid == 0) {
    float t0 = 0.f, t1 = 0.f, t2 = 0.f, t3 = 0.f;
    for (int w = 0; w < 4; ++w) {
      t0 += red[w][lane][0]; t1 += red[w][lane][1];
      t2 += red[w][lane][2]; t3 += red[w][lane][3];
    }
    atomicAdd(&stats[ST_SUM2 + lane], t0);
    atomicAdd(&stats[ST_SQ2 + lane], t1);
    atomicAdd(&stats[ST_SUM2 + 64 + lane], t2);
    atomicAdd(&stats[ST_SQ2 + 64 + lane], t3);
  }
}

// ==================================================================
// 7) BN2 + relu + max over nsample, transposed write via LDS tile
//    block = (b, 64-m tile); out x shape (8,128,1024)
// ==================================================================
__global__ __launch_bounds__(256) void k7_kernel(const __hip_bfloat16* __restrict__ z2,
                                                 const float* __restrict__ stats,
                                                 float* __restrict__ out3) {
  const int b = blockIdx.x >> 4;
  const int mt = blockIdx.x & 15;
  const int t = threadIdx.x;
  const int o = t & 127, h = t >> 7;
  const float a = stats[P_A2 + o], bb = stats[P_B2 + o];
  __shared__ float tile[128][65];
  for (int j = 0; j < 32; ++j) {
    const int ml = h + 2 * j;
    const size_t rowbase = ((size_t)(b * 1024 + mt * 64 + ml)) * SS;
    float acc = -1e30f;
    for (int s = 0; s < SS; ++s) {
      const float v = __bfloat162float(z2[(rowbase + s) * 128 + o]);
      acc = fmaxf(acc, a * v + bb);
    }
    tile[o][ml] = fmaxf(acc, 0.f);                 // relu after max (monotone)
  }
  __syncthreads();
  const int r = t >> 1, c0 = (t & 1) * 32;
  float* dst = out3 + (size_t)b * 128 * 1024 + (size_t)r * 1024 + mt * 64 + c0;
  for (int j = 0; j < 32; ++j) dst[j] = tile[r][c0 + j];
}

// ==================================================================
extern "C" void kernel_launch(void* const* d_in, const int* in_sizes, int n_in,
                              void* d_out, int out_size, void* d_ws, size_t ws_size,
                              hipStream_t stream) {
  const float* center  = (const float*)d_in[0];
  const float* normal  = (const float*)d_in[1];
  const float* feature = (const float*)d_in[2];
  const float* w_l0 = (const float*)d_in[3];
  const float* b_l0 = (const float*)d_in[4];
  const float* g_l0 = (const float*)d_in[5];
  const float* be_l0 = (const float*)d_in[6];
  const float* w_f0 = (const float*)d_in[7];
  const float* b_f0 = (const float*)d_in[8];
  const float* g_f0 = (const float*)d_in[9];
  const float* be_f0 = (const float*)d_in[10];
  const float* w1 = (const float*)d_in[11];
  const float* b1 = (const float*)d_in[12];
  const float* g1 = (const float*)d_in[13];
  const float* be1 = (const float*)d_in[14];
  const float* w2 = (const float*)d_in[15];
  const float* b2 = (const float*)d_in[16];
  const float* g2 = (const float*)d_in[17];
  const float* be2 = (const float*)d_in[18];
  float* out = (float*)d_out;
  char* ws = (char*)d_ws;
  int*   fps_idx = (int*)(ws + OFF_FPS);
  float* stats   = (float*)(ws + OFF_STATS);
  float* x0      = (float*)(ws + OFF_X0);
  float* z1      = (float*)(ws + OFF_Z1);

  hipMemsetAsync(stats, 0, STATS_ZERO_BYTES, stream);
  hipLaunchKernelGGL(fps_kernel, dim3(8), dim3(256), 0, stream, center, fps_idx);
  hipLaunchKernelGGL(ball_gather_kernel, dim3(2048), dim3(256), 0, stream,
                     center, normal, feature, fps_idx, x0, out);
  hipLaunchKernelGGL(stats0_kernel, dim3(512), dim3(256), 0, stream,
                     x0, w_l0, b_l0, w_f0, b_f0, stats);
  hipLaunchKernelGGL(finalize0_kernel, dim3(1), dim3(128), 0, stream,
                     stats, g_l0, be_l0, g_f0, be_f0);
  hipLaunchKernelGGL(k5_kernel, dim3(512), dim3(256), 0, stream,
                     x0, z1, stats, w_l0, b_l0, w_f0, b_f0, w1, b1);
  hipLaunchKernelGGL(finalize1_kernel, dim3(1), dim3(64), 0, stream, stats, g1, be1);
  hipLaunchKernelGGL(k6_kernel, dim3(512), dim3(256), 0, stream, z1, stats, w2, b2);
  hipLaunchKernelGGL(finalize2_kernel, dim3(1), dim3(128), 0, stream, stats, g2, be2);
  hipLaunchKernelGGL(k7_kernel, dim3(128), dim3(256), 0, stream,
                     (const __hip_bfloat16*)z1, stats, out + 49152);
}

// Round 6
// 1308.469 us; speedup vs baseline: 1.3374x; 1.0631x over previous
//
#include <hip/hip_runtime.h>
#include <hip/hip_bf16.h>
#include <cstdint>
#include <cstddef>

// ---------------- problem constants ----------------
#define BB 8
#define NN 8192
#define MM 1024
#define SS 32
#define PTOT (BB*MM*SS)          // 262144
// threshold must match f32(0.2*0.2 computed in double) — NOT 0.2f*0.2f
__device__ __constant__ float kR2 = 0.039999999105930328f;

// ---------------- stats layout (float offsets in ws) ----------------
#define ST_SUM0L 0
#define ST_SQ0L  64
#define ST_SUM0F 128
#define ST_SQ0F  192
#define ST_SUM1  256
#define ST_SQ1   320
#define ST_SUM2  384
#define ST_SQ2   512
#define P_AL     640
#define P_BL     704
#define P_AF     768
#define P_BF     832
#define P_A1     896
#define P_B1     960
#define P_A2     1024
#define P_B2     1152
#define STATS_ZERO_BYTES (640*4)

// ws byte offsets
#define OFF_FPS   0u
#define OFF_STATS 32768u
#define OFF_X0    40960u
#define OFF_Z1    12623872u      // x0 ends at 40960 + 262144*48 = 12623872

typedef float v2f __attribute__((ext_vector_type(2)));
typedef unsigned long long ull;

// u64-key max over DPP (rocPRIM wave64 ctrl sequence, validated R3/R4).
// Both halves use identical ctrl/masks -> pair comes from the same lane;
// masked/out-of-bounds lanes keep own value (max(v,v)=v harmless).
#define DPP_KMAX(k, ctrl, rm, bm) {                                        \
  const unsigned _lo = (unsigned)(k), _hi = (unsigned)((k) >> 32);         \
  const unsigned _nl = (unsigned)__builtin_amdgcn_update_dpp(              \
      (int)_lo, (int)_lo, ctrl, rm, bm, false);                            \
  const unsigned _nh = (unsigned)__builtin_amdgcn_update_dpp(              \
      (int)_hi, (int)_hi, ctrl, rm, bm, false);                            \
  const ull _o = ((ull)_nh << 32) | _nl;                                   \
  k = (_o > (k)) ? _o : (k); }

// ==================================================================
// 1) FPS v9: coords pinned in registers (R2); argmax via single u64
//    key reduce: key = (f32bits(T)<<32) | ~idx. Non-negative float
//    bits order as unsigned -> max key == max distance, lowest index
//    on ties (np.argmax semantics; same key construction as the
//    proven R0-R2 butterfly). Replaces R3/R4's
//    {tree-max -> DPP fmax -> readlane -> 32-deep serial scan ->
//     DPP umin -> readlane} with:
//      L0: u32 cmp of float bits (ties pick slot 2j = lower idx,
//          valid because ~idx_2j > ~idx_2j+1), 16x(cmp+2sel)
//      L1-4: u64 max tree, 15x(cmp_u64+2sel), depth 4
//      6 DPP u64 max steps; lane 63 writes the wave key directly
//    -> no readlane round-trips, no serial cndmask chain.
//    ~idx constants hoisted into 32 regs outside the loop.
//    Distance op order unchanged (contract off) -> bit-identical d.
// ==================================================================
__global__ __launch_bounds__(256, 1) void fps_kernel(const float* __restrict__ center,
                                                     int* __restrict__ fps_idx) {
  const int b = blockIdx.x;
  const int t = threadIdx.x;               // 0..255
  const int lane = t & 63, wid = t >> 6;   // 4 waves
  const float* cb = center + (size_t)b * NN * 3;
  __shared__ __align__(16) float4 sc[NN];            // 128 KB centroid table
  __shared__ ull s_wkey[2][4];
  v2f X[16], Y[16], Z[16], T[16];
  unsigned nidx[32];
#pragma unroll
  for (int j = 0; j < 16; ++j) {
    const int p0 = ((2 * j) << 8) | t;
    const int p1 = ((2 * j + 1) << 8) | t;
    const float x0 = cb[p0 * 3 + 0], y0 = cb[p0 * 3 + 1], z0 = cb[p0 * 3 + 2];
    const float x1 = cb[p1 * 3 + 0], y1 = cb[p1 * 3 + 1], z1 = cb[p1 * 3 + 2];
    sc[p0] = make_float4(x0, y0, z0, 0.f);
    sc[p1] = make_float4(x1, y1, z1, 0.f);
    X[j] = (v2f){x0, x1}; Y[j] = (v2f){y0, y1}; Z[j] = (v2f){z0, z1};
    T[j] = (v2f){1e10f, 1e10f};
    // pin: asm-defined values cannot be rematerialized from memory
    asm volatile("" : "+v"(X[j]), "+v"(Y[j]), "+v"(Z[j]));
  }
#pragma unroll
  for (int k = 0; k < 32; ++k) nidx[k] = ~(unsigned)((k << 8) | t);
  __syncthreads();
  int far = 0;
  for (int i = 0; i < MM; ++i) {
    if (t == 0) fps_idx[(b << 10) + i] = far;
    // centroid: uniform-address LDS broadcast read
    const float4 c = sc[__builtin_amdgcn_readfirstlane(far)];
    const v2f cx2 = (v2f){c.x, c.x};
    const v2f cy2 = (v2f){c.y, c.y};
    const v2f cz2 = (v2f){c.z, c.z};
    {
#pragma clang fp contract(off)
#pragma unroll
      for (int j = 0; j < 16; ++j) {
        const v2f dx = X[j] - cx2;
        const v2f dy = Y[j] - cy2;
        const v2f dz = Z[j] - cz2;
        v2f d = dx * dx;
        d = d + dy * dy;
        d = d + dz * dz;
        T[j] = __builtin_elementwise_min(T[j], d);
      }
    }
    // ---- per-thread u64 key tree (max dist, lowest idx on ties) ----
    ull K[16];
#pragma unroll
    for (int j = 0; j < 16; ++j) {
      const unsigned hx = __float_as_uint(T[j].x);
      const unsigned hy = __float_as_uint(T[j].y);
      const bool ygt = hy > hx;            // tie -> keep x (lower idx)
      const unsigned h = ygt ? hy : hx;
      const unsigned l = ygt ? nidx[2 * j + 1] : nidx[2 * j];
      K[j] = ((ull)h << 32) | l;
    }
#pragma unroll
    for (int s = 8; s >= 1; s >>= 1) {
#pragma unroll
      for (int j = 0; j < s; ++j) {
        const ull o = K[j + s];
        if (o > K[j]) K[j] = o;
      }
    }
    ull key = K[0];
    // ---- wave u64 max via DPP (lane 63 ends with the full reduce) ----
    DPP_KMAX(key, 0x111, 0xf, 0xf)
    DPP_KMAX(key, 0x112, 0xf, 0xf)
    DPP_KMAX(key, 0x114, 0xf, 0xe)
    DPP_KMAX(key, 0x118, 0xf, 0xc)
    DPP_KMAX(key, 0x142, 0xa, 0xf)
    DPP_KMAX(key, 0x143, 0xc, 0xf)
    if (lane == 63) s_wkey[i & 1][wid] = key;
    __syncthreads();
    const ull* sk = s_wkey[i & 1];
    const ull k0 = sk[0], k1 = sk[1], k2 = sk[2], k3 = sk[3];
    const ull h0 = (k1 > k0) ? k1 : k0;
    const ull h1 = (k3 > k2) ? k3 : k2;
    const ull best = (h1 > h0) ? h1 : h0;
    far = (int)(~(unsigned)best);
  }
}

// ==================================================================
// 2) Ball query (first 32 smallest in-radius indices) + gather + concat
//    one wave per (b,m); also writes new_center/new_normal outputs
// ==================================================================
__global__ __launch_bounds__(256) void ball_gather_kernel(
    const float* __restrict__ center, const float* __restrict__ normal,
    const float* __restrict__ feature, const int* __restrict__ fps_idx,
    float* __restrict__ x0, float* __restrict__ out) {
  const int lane = threadIdx.x & 63;
  const int wq = (int)((blockIdx.x * blockDim.x + threadIdx.x) >> 6); // 0..8191
  const int b = wq >> 10, m = wq & 1023;
  const float* cb = center  + (size_t)b * NN * 3;
  const float* nb = normal  + (size_t)b * NN * 3;
  const float* fb = feature + (size_t)b * 6 * NN;
  const int pstar = fps_idx[(b << 10) + m];
  const float qx = cb[pstar * 3 + 0], qy = cb[pstar * 3 + 1], qz = cb[pstar * 3 + 2];
  if (lane < 3) {
    out[b * 3072 + lane * 1024 + m]         = cb[pstar * 3 + lane];   // new_center^T
    out[24576 + b * 3072 + lane * 1024 + m] = nb[pstar * 3 + lane];   // new_normal^T
  }
  const size_t pos_base = (size_t)((b << 10) + m) * SS;
  int total = 0;
  int first_p = -1;
  const float r2 = kR2;
  for (int base = 0; base < NN && total < SS; base += 64) {
    const int p = base + lane;
    const float ppx = cb[p * 3], ppy = cb[p * 3 + 1], ppz = cb[p * 3 + 2];
    const float dx = ppx - qx, dy = ppy - qy, dz = ppz - qz;
    float d2;
    {
#pragma clang fp contract(off)
      d2 = dx * dx;
      d2 = d2 + dy * dy;
      d2 = d2 + dz * dz;
    }
    const bool hit = d2 < r2;
    const unsigned long long msk = __ballot(hit);
    if (first_p < 0 && msk) first_p = base + (int)__builtin_ctzll(msk);
    const int rank = (int)__popcll(msk & ((1ull << lane) - 1ull));
    const int slot = total + rank;
    if (hit && slot < SS) {
      float4 v0, v1, v2;
      v0.x = dx; v0.y = dy; v0.z = dz;             // group_center - new_center
      v0.w = nb[p * 3 + 0];
      v1.x = nb[p * 3 + 1];
      v1.y = nb[p * 3 + 2];
      v1.z = fb[p];
      v1.w = fb[NN + p];
      v2.x = fb[2 * NN + p];
      v2.y = fb[3 * NN + p];
      v2.z = fb[4 * NN + p];
      v2.w = fb[5 * NN + p];
      float4* dst = (float4*)(x0 + (pos_base + (size_t)slot) * 12);
      dst[0] = v0; dst[1] = v1; dst[2] = v2;
    }
    total += (int)__popcll(msk);
  }
  if (total < SS) {                                // pad with first hit (ref semantics)
    if (first_p < 0) first_p = 0;
    const int p = first_p;
    const float ppx = cb[p * 3], ppy = cb[p * 3 + 1], ppz = cb[p * 3 + 2];
    float4 v0, v1, v2;
    v0.x = ppx - qx; v0.y = ppy - qy; v0.z = ppz - qz;
    v0.w = nb[p * 3 + 0]; v1.x = nb[p * 3 + 1]; v1.y = nb[p * 3 + 2];
    v1.z = fb[p]; v1.w = fb[NN + p];
    v2.x = fb[2 * NN + p]; v2.y = fb[3 * NN + p]; v2.z = fb[4 * NN + p]; v2.w = fb[5 * NN + p];
    for (int slot = total + lane; slot < SS; slot += 64) {
      float4* dst = (float4*)(x0 + (pos_base + (size_t)slot) * 12);
      dst[0] = v0; dst[1] = v1; dst[2] = v2;
    }
  }
}

// ==================================================================
// 3) stats for layer0 conv outputs (loc 64ch + ftr 64ch), lane = channel
// ==================================================================
__global__ __launch_bounds__(256) void stats0_kernel(
    const float* __restrict__ x0,
    const float* __restrict__ w_l0, const float* __restrict__ b_l0,
    const float* __restrict__ w_f0, const float* __restrict__ b_f0,
    float* __restrict__ stats) {
  const int lane = threadIdx.x & 63, wid = threadIdx.x >> 6;
  const int wgid = blockIdx.x * 4 + wid;           // 0..2047
  float wl[3], wf[9];
#pragma unroll
  for (int j = 0; j < 3; ++j) wl[j] = w_l0[lane * 3 + j];
#pragma unroll
  for (int j = 0; j < 9; ++j) wf[j] = w_f0[lane * 9 + j];
  const float bl = b_l0[lane], bf = b_f0[lane];
  float sL = 0.f, qL = 0.f, sF = 0.f, qF = 0.f;
  for (int it = 0; it < 128; ++it) {
    const int p = it * 2048 + wgid;
    const float4* row = (const float4*)(x0 + (size_t)p * 12);
    const float4 r0 = row[0], r1 = row[1], r2 = row[2];
    const float yL = bl + wl[0] * r0.x + wl[1] * r0.y + wl[2] * r0.z;
    const float yF = bf + wf[0] * r0.w + wf[1] * r1.x + wf[2] * r1.y + wf[3] * r1.z +
                     wf[4] * r1.w + wf[5] * r2.x + wf[6] * r2.y + wf[7] * r2.z + wf[8] * r2.w;
    sL += yL; qL += yL * yL; sF += yF; qF += yF * yF;
  }
  __shared__ float red[4][64][4];
  red[wid][lane][0] = sL; red[wid][lane][1] = qL;
  red[wid][lane][2] = sF; red[wid][lane][3] = qF;
  __syncthreads();
  if (wid == 0) {
    float a0 = 0.f, a1 = 0.f, a2 = 0.f, a3 = 0.f;
    for (int w = 0; w < 4; ++w) {
      a0 += red[w][lane][0]; a1 += red[w][lane][1];
      a2 += red[w][lane][2]; a3 += red[w][lane][3];
    }
    atomicAdd(&stats[ST_SUM0L + lane], a0);
    atomicAdd(&stats[ST_SQ0L + lane], a1);
    atomicAdd(&stats[ST_SUM0F + lane], a2);
    atomicAdd(&stats[ST_SQ0F + lane], a3);
  }
}

// ==================================================================
// finalize kernels: sums -> (a, b') with y_norm = a*y + b'
// ==================================================================
__global__ void finalize0_kernel(float* stats, const float* gl, const float* bel,
                                 const float* gf, const float* bef) {
  const int t = threadIdx.x;                        // 128
  const float invN = 1.0f / (float)PTOT;
  if (t < 64) {
    const float mean = stats[ST_SUM0L + t] * invN;
    const float var  = stats[ST_SQ0L + t] * invN - mean * mean;
    const float a = gl[t] / sqrtf(var + 1e-5f);
    stats[P_AL + t] = a;
    stats[P_BL + t] = bel[t] - a * mean;
  } else {
    const int c = t - 64;
    const float mean = stats[ST_SUM0F + c] * invN;
    const float var  = stats[ST_SQ0F + c] * invN - mean * mean;
    const float a = gf[c] / sqrtf(var + 1e-5f);
    stats[P_AF + c] = a;
    stats[P_BF + c] = bef[c] - a * mean;
  }
}
__global__ void finalize1_kernel(float* stats, const float* g, const float* be) {
  const int t = threadIdx.x;                        // 64
  const float invN = 1.0f / (float)PTOT;
  const float mean = stats[ST_SUM1 + t] * invN;
  const float var  = stats[ST_SQ1 + t] * invN - mean * mean;
  const float a = g[t] / sqrtf(var + 1e-5f);
  stats[P_A1 + t] = a;
  stats[P_B1 + t] = be[t] - a * mean;
}
__global__ void finalize2_kernel(float* stats, const float* g, const float* be) {
  const int t = threadIdx.x;                        // 128
  const float invN = 1.0f / (float)PTOT;
  const float mean = stats[ST_SUM2 + t] * invN;
  const float var  = stats[ST_SQ2 + t] * invN - mean * mean;
  const float a = g[t] / sqrtf(var + 1e-5f);
  stats[P_A2 + t] = a;
  stats[P_B2 + t] = be[t] - a * mean;
}

// ==================================================================
// 5) conv0 + BN0 + relu  ->  conv1 (z1 stored f32) + stats1
//    lane = output channel; per-position x1 broadcast via wave-private LDS
// ==================================================================
__global__ __launch_bounds__(256) void k5_kernel(
    const float* __restrict__ x0, float* __restrict__ z1,
    float* __restrict__ stats,
    const float* __restrict__ w_l0, const float* __restrict__ b_l0,
    const float* __restrict__ w_f0, const float* __restrict__ b_f0,
    const float* __restrict__ w1, const float* __restrict__ b1) {
  const int lane = threadIdx.x & 63, wid = threadIdx.x >> 6;
  const int wgid = blockIdx.x * 4 + wid;
  float wl[3], wf[9], w1r[64];
#pragma unroll
  for (int j = 0; j < 3; ++j) wl[j] = w_l0[lane * 3 + j];
#pragma unroll
  for (int j = 0; j < 9; ++j) wf[j] = w_f0[lane * 9 + j];
#pragma unroll
  for (int k = 0; k < 64; ++k) w1r[k] = w1[lane * 64 + k];
  const float bl = b_l0[lane], bf = b_f0[lane], b1v = b1[lane];
  const float aL = stats[P_AL + lane], bL = stats[P_BL + lane];
  const float aF = stats[P_AF + lane], bF = stats[P_BF + lane];
  float s1 = 0.f, q1 = 0.f;
  __shared__ __align__(16) float sx[2][4][64];
  for (int it = 0; it < 128; ++it) {
    const int p = it * 2048 + wgid;
    const float4* row = (const float4*)(x0 + (size_t)p * 12);
    const float4 r0 = row[0], r1 = row[1], r2 = row[2];
    const float yL = bl + wl[0] * r0.x + wl[1] * r0.y + wl[2] * r0.z;
    const float yF = bf + wf[0] * r0.w + wf[1] * r1.x + wf[2] * r1.y + wf[3] * r1.z +
                     wf[4] * r1.w + wf[5] * r2.x + wf[6] * r2.y + wf[7] * r2.z + wf[8] * r2.w;
    const float x1 = fmaxf(aL * yL + bL + (aF * yF + bF), 0.f);
    sx[it & 1][wid][lane] = x1;
    __syncthreads();
    float acc = b1v;
    const float4* xv = (const float4*)&sx[it & 1][wid][0];
#pragma unroll
    for (int k4 = 0; k4 < 16; ++k4) {
      const float4 xq = xv[k4];
      acc += w1r[4 * k4 + 0] * xq.x + w1r[4 * k4 + 1] * xq.y +
             w1r[4 * k4 + 2] * xq.z + w1r[4 * k4 + 3] * xq.w;
    }
    s1 += acc; q1 += acc * acc;
    z1[(size_t)p * 64 + lane] = acc;
  }
  __shared__ float red[4][64][2];
  red[wid][lane][0] = s1; red[wid][lane][1] = q1;
  __syncthreads();
  if (wid == 0) {
    float a0 = 0.f, a1v = 0.f;
    for (int w = 0; w < 4; ++w) { a0 += red[w][lane][0]; a1v += red[w][lane][1]; }
    atomicAdd(&stats[ST_SUM1 + lane], a0);
    atomicAdd(&stats[ST_SQ1 + lane], a1v);
  }
}

// ==================================================================
// 6) BN1+relu -> conv2 (128ch) + stats2; z2 written bf16 IN-PLACE over z1
// ==================================================================
__global__ __launch_bounds__(256, 2) void k6_kernel(
    float* __restrict__ z12, float* __restrict__ stats,
    const float* __restrict__ w2, const float* __restrict__ b2) {
  const int lane = threadIdx.x & 63, wid = threadIdx.x >> 6;
  const int wgid = blockIdx.x * 4 + wid;
  float w2a[64], w2b[64];
#pragma unroll
  for (int k = 0; k < 64; ++k) w2a[k] = w2[lane * 64 + k];
#pragma unroll
  for (int k = 0; k < 64; ++k) w2b[k] = w2[(lane + 64) * 64 + k];
  const float b2a = b2[lane], b2b = b2[lane + 64];
  const float a1 = stats[P_A1 + lane], b1p = stats[P_B1 + lane];
  float s0 = 0.f, q0 = 0.f, s1 = 0.f, q1 = 0.f;
  __shared__ __align__(16) float sx[2][4][64];
  __hip_bfloat16* zo = (__hip_bfloat16*)z12;
  for (int it = 0; it < 128; ++it) {
    const int p = it * 2048 + wgid;
    const float z = z12[(size_t)p * 64 + lane];
    const float x2 = fmaxf(a1 * z + b1p, 0.f);
    sx[it & 1][wid][lane] = x2;
    __syncthreads();
    float acc0 = b2a, acc1 = b2b;
    const float4* xv = (const float4*)&sx[it & 1][wid][0];
#pragma unroll
    for (int k4 = 0; k4 < 16; ++k4) {
      const float4 xq = xv[k4];
      acc0 += w2a[4 * k4] * xq.x + w2a[4 * k4 + 1] * xq.y + w2a[4 * k4 + 2] * xq.z + w2a[4 * k4 + 3] * xq.w;
      acc1 += w2b[4 * k4] * xq.x + w2b[4 * k4 + 1] * xq.y + w2b[4 * k4 + 2] * xq.z + w2b[4 * k4 + 3] * xq.w;
    }
    s0 += acc0; q0 += acc0 * acc0; s1 += acc1; q1 += acc1 * acc1;
    zo[(size_t)p * 128 + lane]      = __float2bfloat16(acc0);
    zo[(size_t)p * 128 + 64 + lane] = __float2bfloat16(acc1);
  }
  __shared__ float red[4][64][4];
  red[wid][lane][0] = s0; red[wid][lane][1] = q0;
  red[wid][lane][2] = s1; red[wid][lane][3] = q1;
  __syncthreads();
  if (wid == 0) {
    float t0 = 0.f, t1 = 0.f, t2 = 0.f, t3 = 0.f;
    for (int w = 0; w < 4; ++w) {
      t0 += red[w][lane][0]; t1 += red[w][lane][1];
      t2 += red[w][lane][2]; t3 += red[w][lane][3];
    }
    atomicAdd(&stats[ST_SUM2 + lane], t0);
    atomicAdd(&stats[ST_SQ2 + lane], t1);
    atomicAdd(&stats[ST_SUM2 + 64 + lane], t2);
    atomicAdd(&stats[ST_SQ2 + 64 + lane], t3);
  }
}

// ==================================================================
// 7) BN2 + relu + max over nsample, transposed write via LDS tile
//    block = (b, 64-m tile); out x shape (8,128,1024)
// ==================================================================
__global__ __launch_bounds__(256) void k7_kernel(const __hip_bfloat16* __restrict__ z2,
                                                 const float* __restrict__ stats,
                                                 float* __restrict__ out3) {
  const int b = blockIdx.x >> 4;
  const int mt = blockIdx.x & 15;
  const int t = threadIdx.x;
  const int o = t & 127, h = t >> 7;
  const float a = stats[P_A2 + o], bb = stats[P_B2 + o];
  __shared__ float tile[128][65];
  for (int j = 0; j < 32; ++j) {
    const int ml = h + 2 * j;
    const size_t rowbase = ((size_t)(b * 1024 + mt * 64 + ml)) * SS;
    float acc = -1e30f;
    for (int s = 0; s < SS; ++s) {
      const float v = __bfloat162float(z2[(rowbase + s) * 128 + o]);
      acc = fmaxf(acc, a * v + bb);
    }
    tile[o][ml] = fmaxf(acc, 0.f);                 // relu after max (monotone)
  }
  __syncthreads();
  const int r = t >> 1, c0 = (t & 1) * 32;
  float* dst = out3 + (size_t)b * 128 * 1024 + (size_t)r * 1024 + mt * 64 + c0;
  for (int j = 0; j < 32; ++j) dst[j] = tile[r][c0 + j];
}

// ==================================================================
extern "C" void kernel_launch(void* const* d_in, const int* in_sizes, int n_in,
                              void* d_out, int out_size, void* d_ws, size_t ws_size,
                              hipStream_t stream) {
  const float* center  = (const float*)d_in[0];
  const float* normal  = (const float*)d_in[1];
  const float* feature = (const float*)d_in[2];
  const float* w_l0 = (const float*)d_in[3];
  const float* b_l0 = (const float*)d_in[4];
  const float* g_l0 = (const float*)d_in[5];
  const float* be_l0 = (const float*)d_in[6];
  const float* w_f0 = (const float*)d_in[7];
  const float* b_f0 = (const float*)d_in[8];
  const float* g_f0 = (const float*)d_in[9];
  const float* be_f0 = (const float*)d_in[10];
  const float* w1 = (const float*)d_in[11];
  const float* b1 = (const float*)d_in[12];
  const float* g1 = (const float*)d_in[13];
  const float* be1 = (const float*)d_in[14];
  const float* w2 = (const float*)d_in[15];
  const float* b2 = (const float*)d_in[16];
  const float* g2 = (const float*)d_in[17];
  const float* be2 = (const float*)d_in[18];
  float* out = (float*)d_out;
  char* ws = (char*)d_ws;
  int*   fps_idx = (int*)(ws + OFF_FPS);
  float* stats   = (float*)(ws + OFF_STATS);
  float* x0      = (float*)(ws + OFF_X0);
  float* z1      = (float*)(ws + OFF_Z1);

  hipMemsetAsync(stats, 0, STATS_ZERO_BYTES, stream);
  hipLaunchKernelGGL(fps_kernel, dim3(8), dim3(256), 0, stream, center, fps_idx);
  hipLaunchKernelGGL(ball_gather_kernel, dim3(2048), dim3(256), 0, stream,
                     center, normal, feature, fps_idx, x0, out);
  hipLaunchKernelGGL(stats0_kernel, dim3(512), dim3(256), 0, stream,
                     x0, w_l0, b_l0, w_f0, b_f0, stats);
  hipLaunchKernelGGL(finalize0_kernel, dim3(1), dim3(128), 0, stream,
                     stats, g_l0, be_l0, g_f0, be_f0);
  hipLaunchKernelGGL(k5_kernel, dim3(512), dim3(256), 0, stream,
                     x0, z1, stats, w_l0, b_l0, w_f0, b_f0, w1, b1);
  hipLaunchKernelGGL(finalize1_kernel, dim3(1), dim3(64), 0, stream, stats, g1, be1);
  hipLaunchKernelGGL(k6_kernel, dim3(512), dim3(256), 0, stream, z1, stats, w2, b2);
  hipLaunchKernelGGL(finalize2_kernel, dim3(1), dim3(128), 0, stream, stats, g2, be2);
  hipLaunchKernelGGL(k7_kernel, dim3(128), dim3(256), 0, stream,
                     (const __hip_bfloat16*)z1, stats, out + 49152);
}